// Round 5
// baseline (185.495 us; speedup 1.0000x reference)
//
#include <hip/hip_runtime.h>
#include <stdint.h>

// Bit-exact f32 vs numpy reference required for label thresholds:
// kill FMA contraction everywhere.
#pragma clang fp contract(off)

#define NB 16       // batch
#define NA 12       // anchors per cell
#define NH 64
#define NW 64
#define NG 64       // gt boxes per batch
#define NN (NA*NH*NW)   // 49152 anchors per batch row
#define NBLK (NN/256)   // 192 k_main blocks per batch row
#define NCH 16          // k_post chunks per row
#define CHSZ (NN/NCH)   // 3072 anchors per k_post block
#define CAP 2048        // coarse-boundary-bin list capacity (expected ~110)

// ws layout (uint32 index) — nothing needs pre-zeroing:
// [0 .. 3072)                      per-block packed (pos<<16|neg) partials
// [4096 .. 4096+3072*128)          per-block 256-bin u16-pair hists (512B each)
// [WS_RNK .. WS_RNK+NB*NN)         rnk32 = (u23<<2)|lab2 per anchor (optional)
#define WS_PART 0
#define WS_BH   4096
#define WS_RNK  (WS_BH + NB*NBLK*128)     // 397312
#define WS_NEED_BH  ((size_t)WS_RNK * 4)
#define WS_NEED_RNK (((size_t)WS_RNK + (size_t)NB*NN) * 4)   // ~4.5 MB

__device__ __forceinline__ uint32_t rotl32(uint32_t x, int r) {
    return (x << r) | (x >> (32 - r));
}

// threefry2x32, key = jax.random.key(42) -> (0, 42), partitionable counters:
// x0 = hi(flat_idx)=0, x1 = lo(flat_idx)=i; 32-bit draw = out0 ^ out1.
// Verified bit-exact (absmax 0 in R1-R4).
__device__ uint32_t threefry_bits(uint32_t idx) {
    const uint32_t ks0 = 0u, ks1 = 42u, ks2 = 0x1BD11BDAu ^ 0u ^ 42u;
    uint32_t x0 = ks0;
    uint32_t x1 = idx + ks1;
#define RND(r) { x0 += x1; x1 = rotl32(x1, r); x1 ^= x0; }
    RND(13) RND(15) RND(26) RND(6)
    x0 += ks1; x1 += ks2 + 1u;
    RND(17) RND(29) RND(16) RND(24)
    x0 += ks2; x1 += ks0 + 2u;
    RND(13) RND(15) RND(26) RND(6)
    x0 += ks0; x1 += ks1 + 3u;
    RND(17) RND(29) RND(16) RND(24)
    x0 += ks1; x1 += ks2 + 4u;
    RND(13) RND(15) RND(26) RND(6)
    x0 += ks2; x1 += ks0 + 5u;
#undef RND
    return x0 ^ x1;
}

// Division-free argmax (verified bit-exact R1-R4): fractions (num, den),
// ov==0 represented exactly as 1e-10/1; cross-mult compare with 2^-20 guard
// band, rare in-band fallback does the two IEEE divisions.
__global__ __launch_bounds__(256) void k_main(const float4* __restrict__ gt,
                                              const float4* __restrict__ anc,
                                              float* __restrict__ out,
                                              uint32_t* __restrict__ w,
                                              uint32_t* __restrict__ rnk) {
#pragma clang fp contract(off)
    const int b = blockIdx.y;
    const int n = blockIdx.x * 256 + threadIdx.x;
    const int t = threadIdx.x;

    __shared__ float4 sgv[NG];    // (gx0, gy0, gx1, gy1)
    __shared__ float  sgar[NG];   // gt area
    __shared__ float4 sg0[NG];    // batch-0 boxes (reference gt_flat indexing bug)
    __shared__ float  sout[256 * 5];
    __shared__ uint32_t sred[4];  // per-wave packed (pos<<16 | neg)
    __shared__ uint32_t shist[256];  // coarse (top-8-bit) rank-key hist, label-0
    shist[t] = 0;
    if (t < NG) {
        float4 g = gt[b * NG + t];
        sgv[t] = make_float4(g.x, g.y, g.x + g.z, g.y + g.w);
        sgar[t] = g.z * g.w;
    } else if (t < 2 * NG) {
        sg0[t - NG] = gt[t - NG];
    }
    __syncthreads();

    float4 a = anc[n];
    float ax1 = a.x + a.z;
    float ay1 = a.y + a.w;
    float aar = a.z * a.w;
    bool keep = (a.x >= 0.f) && (a.y >= 0.f) && (a.z >= 0.f) && (a.w >= 0.f)
             && (a.x <= 63.f) && (a.y <= 63.f)
             && ((ax1 - 1.0f) <= 63.f) && ((ay1 - 1.0f) <= 63.f);

    float nb_, db_;            // best fraction
    int ib_ = 0;
    {
        float4 gv = sgv[0];
        float iw = fmaxf(0.0f, fminf(ax1, gv.z) - fmaxf(a.x, gv.x));
        float ih = fmaxf(0.0f, fminf(ay1, gv.w) - fmaxf(a.y, gv.y));
        float inter = iw * ih;
        float uni = (aar + sgar[0]) - inter;
        nb_ = inter; db_ = uni;
        if (inter == 0.0f) { nb_ = 1e-10f; db_ = 1.0f; }
    }
#pragma unroll 4
    for (int g = 1; g < NG; ++g) {
        float4 gv = sgv[g];
        float iw = fmaxf(0.0f, fminf(ax1, gv.z) - fmaxf(a.x, gv.x));
        float ih = fmaxf(0.0f, fminf(ay1, gv.w) - fmaxf(a.y, gv.y));
        float inter = iw * ih;
        float uni = (aar + sgar[g]) - inter;
        float ng_ = inter, dg_ = uni;
        if (inter == 0.0f) { ng_ = 1e-10f; dg_ = 1.0f; }

        float p = ng_ * db_;
        float q = nb_ * dg_;
        float d_ = p - q;
        float band = 0x1p-20f * fmaxf(p, q);
        bool same = (ng_ == nb_) && (dg_ == db_);
        bool nearby = (!same) && (fabsf(d_) <= band);
        bool win;
        if (__builtin_expect(nearby, 0)) {
            float ovg = ng_ / dg_;
            float ovb = nb_ / db_;
            win = ovg > ovb;                        // rounded compare, tie keeps earlier
        } else {
            win = d_ > band;                        // same => d_==0 => false (keep earlier)
        }
        if (win) { nb_ = ng_; db_ = dg_; ib_ = g; }
    }
    float best = nb_ / db_;    // == reference max_ov, bit-exact

    float label = -1.0f;
    if (keep) label = (best >= 0.7f) ? 1.0f : ((best <= 0.3f) ? 0.0f : -1.0f);

    // pos/neg: ballot + LDS combine + one plain store per block (R3 win).
    uint64_t bp = __ballot(keep && (best > 0.7f));   // pos (strict >)
    uint64_t bn = __ballot(keep && (best < 0.3f));   // neg (strict <)
    if ((t & 63) == 0)
        sred[t >> 6] = ((uint32_t)__popcll(bp) << 16) | (uint32_t)__popcll(bn);

    float t0 = 0.f, t1 = 0.f, t2 = 0.f, t3 = 0.f;
    if (keep) {
        float4 g0 = sg0[ib_];                 // always batch-0 (ref bug)
        t0 = a.x - g0.x / 16.0f;
        t1 = a.y - g0.y / 16.0f;
        t2 = a.z - g0.z / 16.0f;
        t3 = a.w - g0.w / 16.0f;
    }

    // Stage to LDS (stride 5, coprime with 32 banks), then coalesced stores.
    sout[t * 5 + 0] = label;
    sout[t * 5 + 1] = t0; sout[t * 5 + 2] = t1;
    sout[t * 5 + 3] = t2; sout[t * 5 + 4] = t3;

    uint32_t idx = (uint32_t)(b * NN + n);
    uint32_t u = threefry_bits(idx) >> 9;     // 23-bit rank key
    if (label == 0.0f) atomicAdd(&shist[u >> 15], 1u);
    if (rnk) {
        uint32_t lab2 = (label == 0.0f) ? 2u : ((label == 1.0f) ? 1u : 0u);
        rnk[idx] = (u << 2) | lab2;
    }

    __syncthreads();
    if (t == 0)
        w[WS_PART + b * NBLK + blockIdx.x] = sred[0] + sred[1] + sred[2] + sred[3];
    if (t < 128)
        w[WS_BH + (b * NBLK + blockIdx.x) * 128 + t] =
            (shist[2 * t] & 0xFFFFu) | (shist[2 * t + 1] << 16);
    float* ob = out + ((size_t)b * NN + (size_t)blockIdx.x * 256) * 5;
#pragma unroll
    for (int k = 0; k < 5; ++k) ob[k * 256 + t] = sout[k * 256 + t];
}

// Grid = (NCH chunks, NB rows) = 256 blocks. Each block redundantly computes
// row-level stats (deterministic -> identical across siblings), then disables
// only its own CHSZ-anchor chunk. No cross-block communication.
__global__ __launch_bounds__(256) void k_post(float* __restrict__ out,
                                              const uint32_t* __restrict__ w,
                                              const uint32_t* __restrict__ rnk) {
    const int b = blockIdx.y;
    const int ch = blockIdx.x;
    const int t = threadIdx.x;
    __shared__ uint32_t hcnt[256];
    __shared__ uint32_t rp[256], rn[256];
    __shared__ uint32_t lu[CAP], li[CAP];   // boundary coarse-bin entries
    __shared__ uint32_t scnt;
    __shared__ int sC;
    __shared__ uint32_t sBase;

    // 1. pos/neg from the 3072 packed partials.
    uint32_t sp = 0, sn = 0;
    for (int i = t; i < NB * NBLK; i += 256) {
        uint32_t v = w[WS_PART + i];
        sp += v >> 16; sn += v & 0xFFFFu;
    }
    rp[t] = sp; rn[t] = sn;
    if (t == 0) scnt = 0;
    __syncthreads();
    for (int s = 128; s > 0; s >>= 1) {
        if (t < s) { rp[t] += rp[t + s]; rn[t] += rn[t + s]; }
        __syncthreads();
    }
    uint32_t pos = rp[0], neg = rn[0];
    uint32_t cutoff = 3u * pos; if (cutoff < 1u) cutoff = 1u;
    if (neg <= cutoff) return;     // uniform across grid: no disabling at all

    // 2. row coarse hist = sum of this row's 192 block-hists (u16 pairs).
    {
        const uint32_t* rbh = w + WS_BH + b * NBLK * 128;
        int d = t >> 1, hi = t & 1;
        uint32_t c = 0;
        for (int blk = 0; blk < NBLK; ++blk) {
            uint32_t v = rbh[blk * 128 + d];
            c += hi ? (v >> 16) : (v & 0xFFFFu);
        }
        hcnt[t] = c;
    }
    __syncthreads();
    if (t == 0) {
        uint32_t cum = 0; int C = -1; uint32_t base = 0;
        for (int c = 255; c >= 0; --c) {
            if (cum + hcnt[c] >= cutoff) { C = c; base = cum; break; }
            cum += hcnt[c];
        }
        sC = C; sBase = base;
    }
    __syncthreads();
    int C = sC;
    if (C < 0) return;             // row has < cutoff label-0 -> keep all

    // 3. full-row pass: collect boundary coarse-bin entries (expected ~110).
    for (int i = t; i < NN; i += 256) {
        uint32_t idx = (uint32_t)(b * NN + i);
        uint32_t u; bool is0;
        if (rnk) {
            uint32_t v = rnk[idx];
            is0 = ((v & 3u) == 2u); u = v >> 2;
        } else {
            is0 = (out[(size_t)idx * 5] == 0.0f);
            u = is0 ? (threefry_bits(idx) >> 9) : 0u;
        }
        if (is0 && (int)(u >> 15) == C) {
            uint32_t p_ = atomicAdd(&scnt, 1u);
            if (p_ < CAP) { lu[p_] = u; li[p_] = (uint32_t)i; }
        }
    }
    __syncthreads();

    // exact rank resolution for boundary entries in MY chunk.
    uint32_t cnt = scnt; if (cnt > CAP) cnt = CAP;
    uint32_t baseRank = sBase;
    for (uint32_t k = t; k < cnt; k += 256) {
        uint32_t u = lu[k], n = li[k];
        if (n / (uint32_t)CHSZ != (uint32_t)ch) continue;
        uint32_t r = baseRank;
        for (uint32_t j = 0; j < cnt; ++j) {
            // descending u, ties by smaller index first (stable argsort)
            r += (lu[j] > u || (lu[j] == u && li[j] < n)) ? 1u : 0u;
        }
        if (r >= cutoff) out[((size_t)b * NN + n) * 5] = -1.0f;
    }

    // 4. my chunk: coarse bin < C -> disabled (bin == C handled above).
    const int start = ch * CHSZ;
    for (int i2 = t; i2 < CHSZ; i2 += 256) {
        int i = start + i2;
        uint32_t idx = (uint32_t)(b * NN + i);
        uint32_t u; bool is0;
        if (rnk) {
            uint32_t v = rnk[idx];
            is0 = ((v & 3u) == 2u); u = v >> 2;
        } else {
            is0 = (out[(size_t)idx * 5] == 0.0f);
            u = is0 ? (threefry_bits(idx) >> 9) : 0u;
        }
        if (is0 && (int)(u >> 15) < C) out[(size_t)idx * 5] = -1.0f;
    }
}

extern "C" void kernel_launch(void* const* d_in, const int* in_sizes, int n_in,
                              void* d_out, int out_size, void* d_ws, size_t ws_size,
                              hipStream_t stream) {
    // d_in[0] = cls_scores (shape-relevant only, never read)
    const float4* gt  = (const float4*)d_in[1];
    const float4* anc = (const float4*)d_in[2];
    float* out = (float*)d_out;
    uint32_t* w = (uint32_t*)d_ws;
    uint32_t* rnk = (ws_size >= WS_NEED_RNK) ? (w + WS_RNK) : (uint32_t*)nullptr;

    k_main<<<dim3(NBLK, NB), 256, 0, stream>>>(gt, anc, out, w, rnk);
    k_post<<<dim3(NCH, NB), 256, 0, stream>>>(out, w, rnk);
}

// Round 6
// 145.079 us; speedup vs baseline: 1.2786x; 1.2786x over previous
//
#include <hip/hip_runtime.h>
#include <stdint.h>

// Bit-exact f32 vs numpy reference required for label thresholds:
// kill FMA contraction everywhere.
#pragma clang fp contract(off)

#define NB 16       // batch
#define NA 12       // anchors per cell
#define NH 64
#define NW 64
#define NG 64       // gt boxes per batch
#define NN (NA*NH*NW)   // 49152 anchors per batch row
#define NBLK (NN/256)   // 192 k_main tiles per batch row
#define NCH 64          // k_post chunks per row (64 x 16 = 1024 blocks)
#define CHSZ (NN/NCH)   // 768 anchors per k_post block
#define CAP 2048        // coarse-boundary-bin list capacity (expected ~137)

// ws layout (uint32 index) — every word is rewritten each launch, nothing
// needs pre-zeroing (harness poisons ws with 0xAA before every call):
// [0 .. 3072)                      per-tile packed (pos<<16|neg) partials
// [4096 .. 4096+NB*128*192)        tile hists, TRANSPOSED [b][word d][tile]
//                                  word d packs bins (2d, 2d+1) as u16 pair
// [WS_RNK .. WS_RNK+NB*NN)         rnk32 = (u23<<2)|lab2 per anchor (optional)
#define WS_PART 0
#define WS_BH   4096
#define WS_RNK  (WS_BH + NB*128*NBLK)     // 397312
#define WS_NEED_RNK (((size_t)WS_RNK + (size_t)NB*NN) * 4)   // ~4.5 MB

__device__ __forceinline__ uint32_t rotl32(uint32_t x, int r) {
    return (x << r) | (x >> (32 - r));
}

// threefry2x32, key = jax.random.key(42) -> (0, 42), partitionable counters:
// x0 = hi(flat_idx)=0, x1 = lo(flat_idx)=i; 32-bit draw = out0 ^ out1.
// Verified bit-exact (absmax 0 in R1-R5).
__device__ uint32_t threefry_bits(uint32_t idx) {
    const uint32_t ks0 = 0u, ks1 = 42u, ks2 = 0x1BD11BDAu ^ 0u ^ 42u;
    uint32_t x0 = ks0;
    uint32_t x1 = idx + ks1;
#define RND(r) { x0 += x1; x1 = rotl32(x1, r); x1 ^= x0; }
    RND(13) RND(15) RND(26) RND(6)
    x0 += ks1; x1 += ks2 + 1u;
    RND(17) RND(29) RND(16) RND(24)
    x0 += ks2; x1 += ks0 + 2u;
    RND(13) RND(15) RND(26) RND(6)
    x0 += ks0; x1 += ks1 + 3u;
    RND(17) RND(29) RND(16) RND(24)
    x0 += ks1; x1 += ks2 + 4u;
    RND(13) RND(15) RND(26) RND(6)
    x0 += ks2; x1 += ks0 + 5u;
#undef RND
    return x0 ^ x1;
}

// Division-free argmax (verified bit-exact R1-R5): fractions (num, den),
// ov==0 represented exactly as 1e-10/1; cross-mult compare with 2^-20 guard
// band, rare in-band fallback does the two IEEE divisions.
__global__ __launch_bounds__(256) void k_main(const float4* __restrict__ gt,
                                              const float4* __restrict__ anc,
                                              float* __restrict__ out,
                                              uint32_t* __restrict__ w,
                                              uint32_t* __restrict__ rnk) {
#pragma clang fp contract(off)
    const int b = blockIdx.y;
    const int n = blockIdx.x * 256 + threadIdx.x;
    const int t = threadIdx.x;

    __shared__ float4 sgv[NG];    // (gx0, gy0, gx1, gy1)
    __shared__ float  sgar[NG];   // gt area
    __shared__ float4 sg0[NG];    // batch-0 boxes (reference gt_flat indexing bug)
    __shared__ float  sout[256 * 5];
    __shared__ uint32_t sred[4];  // per-wave packed (pos<<16 | neg)
    __shared__ uint32_t shist[256];  // coarse (top-8-bit) rank-key hist, label-0
    shist[t] = 0;
    if (t < NG) {
        float4 g = gt[b * NG + t];
        sgv[t] = make_float4(g.x, g.y, g.x + g.z, g.y + g.w);
        sgar[t] = g.z * g.w;
    } else if (t < 2 * NG) {
        sg0[t - NG] = gt[t - NG];
    }
    __syncthreads();

    float4 a = anc[n];
    float ax1 = a.x + a.z;
    float ay1 = a.y + a.w;
    float aar = a.z * a.w;
    bool keep = (a.x >= 0.f) && (a.y >= 0.f) && (a.z >= 0.f) && (a.w >= 0.f)
             && (a.x <= 63.f) && (a.y <= 63.f)
             && ((ax1 - 1.0f) <= 63.f) && ((ay1 - 1.0f) <= 63.f);

    float nb_, db_;            // best fraction
    int ib_ = 0;
    {
        float4 gv = sgv[0];
        float iw = fmaxf(0.0f, fminf(ax1, gv.z) - fmaxf(a.x, gv.x));
        float ih = fmaxf(0.0f, fminf(ay1, gv.w) - fmaxf(a.y, gv.y));
        float inter = iw * ih;
        float uni = (aar + sgar[0]) - inter;
        nb_ = inter; db_ = uni;
        if (inter == 0.0f) { nb_ = 1e-10f; db_ = 1.0f; }
    }
#pragma unroll 4
    for (int g = 1; g < NG; ++g) {
        float4 gv = sgv[g];
        float iw = fmaxf(0.0f, fminf(ax1, gv.z) - fmaxf(a.x, gv.x));
        float ih = fmaxf(0.0f, fminf(ay1, gv.w) - fmaxf(a.y, gv.y));
        float inter = iw * ih;
        float uni = (aar + sgar[g]) - inter;
        float ng_ = inter, dg_ = uni;
        if (inter == 0.0f) { ng_ = 1e-10f; dg_ = 1.0f; }

        float p = ng_ * db_;
        float q = nb_ * dg_;
        float d_ = p - q;
        float band = 0x1p-20f * fmaxf(p, q);
        bool same = (ng_ == nb_) && (dg_ == db_);
        bool nearby = (!same) && (fabsf(d_) <= band);
        bool win;
        if (__builtin_expect(nearby, 0)) {
            float ovg = ng_ / dg_;
            float ovb = nb_ / db_;
            win = ovg > ovb;                        // rounded compare, tie keeps earlier
        } else {
            win = d_ > band;                        // same => d_==0 => false (keep earlier)
        }
        if (win) { nb_ = ng_; db_ = dg_; ib_ = g; }
    }
    float best = nb_ / db_;    // == reference max_ov, bit-exact

    float label = -1.0f;
    if (keep) label = (best >= 0.7f) ? 1.0f : ((best <= 0.3f) ? 0.0f : -1.0f);

    // pos/neg: ballot + LDS combine + one plain store per block (R3 win).
    uint64_t bp = __ballot(keep && (best > 0.7f));   // pos (strict >)
    uint64_t bn = __ballot(keep && (best < 0.3f));   // neg (strict <)
    if ((t & 63) == 0)
        sred[t >> 6] = ((uint32_t)__popcll(bp) << 16) | (uint32_t)__popcll(bn);

    float t0 = 0.f, t1 = 0.f, t2 = 0.f, t3 = 0.f;
    if (keep) {
        float4 g0 = sg0[ib_];                 // always batch-0 (ref bug)
        t0 = a.x - g0.x / 16.0f;
        t1 = a.y - g0.y / 16.0f;
        t2 = a.z - g0.z / 16.0f;
        t3 = a.w - g0.w / 16.0f;
    }

    // Stage to LDS (stride 5, coprime with 32 banks), then coalesced stores.
    sout[t * 5 + 0] = label;
    sout[t * 5 + 1] = t0; sout[t * 5 + 2] = t1;
    sout[t * 5 + 3] = t2; sout[t * 5 + 4] = t3;

    uint32_t idx = (uint32_t)(b * NN + n);
    uint32_t u = threefry_bits(idx) >> 9;     // 23-bit rank key
    if (label == 0.0f) atomicAdd(&shist[u >> 15], 1u);
    if (rnk) {
        uint32_t lab2 = (label == 0.0f) ? 2u : ((label == 1.0f) ? 1u : 0u);
        rnk[idx] = (u << 2) | lab2;
    }

    __syncthreads();
    if (t == 0)
        w[WS_PART + b * NBLK + blockIdx.x] = sred[0] + sred[1] + sred[2] + sred[3];
    // TRANSPOSED tile-hist store: [b][word t][tile] so k_post's merge reads
    // contiguous runs (the R5 merge was 192 strided scalar loads -> latency wall).
    if (t < 128)
        w[WS_BH + (b * 128 + t) * NBLK + blockIdx.x] =
            (shist[2 * t] & 0xFFFFu) | (shist[2 * t + 1] << 16);
    float* ob = out + ((size_t)b * NN + (size_t)blockIdx.x * 256) * 5;
#pragma unroll
    for (int k = 0; k < 5; ++k) ob[k * 256 + t] = sout[k * 256 + t];
}

// Grid = (NCH chunks, NB rows) = 1024 blocks x 256 thr (4 blocks/CU, 16
// waves/CU). Each block redundantly computes row stats (deterministic ->
// identical across siblings), then disables only its CHSZ-anchor chunk.
__global__ __launch_bounds__(256) void k_post(float* __restrict__ out,
                                              const uint32_t* __restrict__ w,
                                              const uint32_t* __restrict__ rnk) {
    const int b = blockIdx.y;
    const int ch = blockIdx.x;
    const int t = threadIdx.x;
    __shared__ uint32_t rp[256], rn[256];
    __shared__ uint32_t sph[256];           // packed per-thread hist partials
    __shared__ uint32_t hcnt[256];          // row coarse hist
    __shared__ uint32_t lu[CAP], li[CAP];   // boundary coarse-bin entries
    __shared__ uint32_t scnt;
    __shared__ int sC;
    __shared__ uint32_t sBase;
    if (t == 0) scnt = 0;

    // 1. pos/neg from the 3072 packed partials (uint4 loads, 3 per thread).
    uint32_t sp = 0, sn = 0;
    {
        const uint4* p4 = (const uint4*)(w + WS_PART);
#pragma unroll
        for (int k = 0; k < 3; ++k) {
            uint4 v = p4[t + k * 256];
            sp += (v.x >> 16) + (v.y >> 16) + (v.z >> 16) + (v.w >> 16);
            sn += (v.x & 0xFFFFu) + (v.y & 0xFFFFu) + (v.z & 0xFFFFu) + (v.w & 0xFFFFu);
        }
    }
    rp[t] = sp; rn[t] = sn;
    __syncthreads();
    for (int s = 128; s > 0; s >>= 1) {
        if (t < s) { rp[t] += rp[t + s]; rn[t] += rn[t + s]; }
        __syncthreads();
    }
    uint32_t pos = rp[0], neg = rn[0];
    uint32_t cutoff = 3u * pos; if (cutoff < 1u) cutoff = 1u;
    if (neg <= cutoff) return;     // uniform across grid: no disabling at all

    // 2. row coarse hist: word d = t>>1 holds bins (2d, 2d+1); its 192 tile
    // values are CONTIGUOUS (transposed layout). 2 threads/word, 24 uint4
    // contiguous loads each. Packed u16 adds safe: 96*256 = 24576 < 65536.
    {
        int d = t >> 1, half = t & 1;
        const uint4* h4 = (const uint4*)(w + WS_BH + (b * 128 + d) * NBLK + half * 96);
        uint32_t c = 0;
#pragma unroll 4
        for (int k = 0; k < 24; ++k) {
            uint4 v = h4[k];
            c += v.x + v.y + v.z + v.w;
        }
        sph[t] = c;
    }
    __syncthreads();
    if (t < 128) {
        uint32_t v0 = sph[2 * t], v1 = sph[2 * t + 1];
        hcnt[2 * t]     = (v0 & 0xFFFFu) + (v1 & 0xFFFFu);
        hcnt[2 * t + 1] = (v0 >> 16) + (v1 >> 16);
    }
    __syncthreads();

    // 3. top-down scan over 256 coarse bins -> boundary bin C, base rank.
    if (t == 0) {
        uint32_t cum = 0; int C = -1; uint32_t base = 0;
        for (int c = 255; c >= 0; --c) {
            if (cum + hcnt[c] >= cutoff) { C = c; base = cum; break; }
            cum += hcnt[c];
        }
        sC = C; sBase = base;
    }
    __syncthreads();
    int C = sC;
    if (C < 0) return;             // row has < cutoff label-0 -> keep all

    // 4a. full-row vectorized scan: collect boundary-bin entries (~137).
    if (rnk) {
        const uint4* r4 = (const uint4*)(rnk + (size_t)b * NN);
        for (int i = t; i < NN / 4; i += 256) {
            uint4 v = r4[i];
            uint32_t vv[4] = {v.x, v.y, v.z, v.w};
#pragma unroll
            for (int k = 0; k < 4; ++k) {
                uint32_t val = vv[k];
                if ((val & 3u) == 2u && (int)((val >> 2) >> 15) == C) {
                    uint32_t p_ = atomicAdd(&scnt, 1u);
                    if (p_ < CAP) { lu[p_] = val >> 2; li[p_] = (uint32_t)(i * 4 + k); }
                }
            }
        }
    } else {
        for (int i = t; i < NN; i += 256) {
            uint32_t idx = (uint32_t)(b * NN + i);
            if (out[(size_t)idx * 5] == 0.0f) {
                uint32_t u = threefry_bits(idx) >> 9;
                if ((int)(u >> 15) == C) {
                    uint32_t p_ = atomicAdd(&scnt, 1u);
                    if (p_ < CAP) { lu[p_] = u; li[p_] = (uint32_t)i; }
                }
            }
        }
    }

    // 4b. own slice: coarse bin < C -> disabled (768 anchors, 1 uint4/thread).
    if (rnk) {
        const uint4* r4 = (const uint4*)(rnk + (size_t)b * NN + (size_t)ch * CHSZ);
        if (t < CHSZ / 4) {
            uint4 v = r4[t];
            uint32_t vv[4] = {v.x, v.y, v.z, v.w};
#pragma unroll
            for (int k = 0; k < 4; ++k) {
                uint32_t val = vv[k];
                if ((val & 3u) == 2u && (int)((val >> 2) >> 15) < C) {
                    int i = ch * CHSZ + t * 4 + k;
                    out[((size_t)b * NN + i) * 5] = -1.0f;
                }
            }
        }
    } else {
        for (int i2 = t; i2 < CHSZ; i2 += 256) {
            int i = ch * CHSZ + i2;
            uint32_t idx = (uint32_t)(b * NN + i);
            if (out[(size_t)idx * 5] == 0.0f) {
                uint32_t u = threefry_bits(idx) >> 9;
                if ((int)(u >> 15) < C) out[(size_t)idx * 5] = -1.0f;
            }
        }
    }
    __syncthreads();

    // 5. exact rank resolution for boundary entries in MY slice.
    uint32_t cnt = scnt; if (cnt > CAP) cnt = CAP;
    uint32_t baseRank = sBase;
    for (uint32_t k = t; k < cnt; k += 256) {
        uint32_t u = lu[k], n = li[k];
        if (n / (uint32_t)CHSZ != (uint32_t)ch) continue;
        uint32_t r = baseRank;
        for (uint32_t j = 0; j < cnt; ++j) {
            // descending u, ties by smaller index first (stable argsort)
            r += (lu[j] > u || (lu[j] == u && li[j] < n)) ? 1u : 0u;
        }
        if (r >= cutoff) out[((size_t)b * NN + n) * 5] = -1.0f;
    }
}

extern "C" void kernel_launch(void* const* d_in, const int* in_sizes, int n_in,
                              void* d_out, int out_size, void* d_ws, size_t ws_size,
                              hipStream_t stream) {
    // d_in[0] = cls_scores (shape-relevant only, never read)
    const float4* gt  = (const float4*)d_in[1];
    const float4* anc = (const float4*)d_in[2];
    float* out = (float*)d_out;
    uint32_t* w = (uint32_t*)d_ws;
    uint32_t* rnk = (ws_size >= WS_NEED_RNK) ? (w + WS_RNK) : (uint32_t*)nullptr;

    k_main<<<dim3(NBLK, NB), 256, 0, stream>>>(gt, anc, out, w, rnk);
    k_post<<<dim3(NCH, NB), 256, 0, stream>>>(out, w, rnk);
}

// Round 7
// 123.101 us; speedup vs baseline: 1.5069x; 1.1785x over previous
//
#include <hip/hip_runtime.h>
#include <stdint.h>

// Bit-exact f32 vs numpy reference required for label thresholds:
// kill FMA contraction everywhere.
#pragma clang fp contract(off)

#define NB 16       // batch
#define NA 12       // anchors per cell
#define NH 64
#define NW 64
#define NG 64       // gt boxes per batch
#define NN (NA*NH*NW)   // 49152 anchors per batch row
#define NBLK (NN/256)   // 192 k_main tiles per batch row
#define NCH 64          // k_post chunks per row (64 x 16 = 1024 blocks)
#define CHSZ (NN/NCH)   // 768 anchors per k_post block
#define CAP 2048        // boundary-bin LDS list capacity (expected ~137)
#define SEGC 8          // segment capacity per (row,bin,tile)

// ws layout (uint32 index) — nothing needs pre-zeroing (counts for segments
// come from the tile hists; harness poisons ws with 0xAA every launch):
// [0 .. 3072)                      per-tile packed (pos<<16|neg) partials
// [4096 ..)                        tile hists, TRANSPOSED [b][word d][tile],
//                                  word d packs bins (2d,2d+1) as u16 pair
// [WS_RNK ..)                      rnk32 = (u23<<2)|lab2 per anchor
// [WS_SEG ..)                      segments [b][bin][tile][slot<SEGC]:
//                                  entry = (u23<<8) | local_n8  (31 bits)
#define WS_PART 0
#define WS_BH   4096
#define WS_RNK  (WS_BH + NB*128*NBLK)                  // 397312
#define WS_SEG  (WS_RNK + NB*NN)                       // 1183744
#define WS_NEED_ALL (((size_t)WS_SEG + (size_t)NB*256*NBLK*SEGC) * 4)  // ~30 MB

__device__ __forceinline__ uint32_t rotl32(uint32_t x, int r) {
    return (x << r) | (x >> (32 - r));
}

// threefry2x32, key = jax.random.key(42) -> (0, 42), partitionable counters:
// x0 = hi(flat_idx)=0, x1 = lo(flat_idx)=i; 32-bit draw = out0 ^ out1.
// Verified bit-exact (absmax 0 in R1-R6).
__device__ uint32_t threefry_bits(uint32_t idx) {
    const uint32_t ks0 = 0u, ks1 = 42u, ks2 = 0x1BD11BDAu ^ 0u ^ 42u;
    uint32_t x0 = ks0;
    uint32_t x1 = idx + ks1;
#define RND(r) { x0 += x1; x1 = rotl32(x1, r); x1 ^= x0; }
    RND(13) RND(15) RND(26) RND(6)
    x0 += ks1; x1 += ks2 + 1u;
    RND(17) RND(29) RND(16) RND(24)
    x0 += ks2; x1 += ks0 + 2u;
    RND(13) RND(15) RND(26) RND(6)
    x0 += ks0; x1 += ks1 + 3u;
    RND(17) RND(29) RND(16) RND(24)
    x0 += ks1; x1 += ks2 + 4u;
    RND(13) RND(15) RND(26) RND(6)
    x0 += ks2; x1 += ks0 + 5u;
#undef RND
    return x0 ^ x1;
}

// Division-free argmax (verified bit-exact R1-R6): fractions (num, den),
// ov==0 represented exactly as 1e-10/1; cross-mult compare with 2^-20 guard
// band, rare in-band fallback does the two IEEE divisions.
__global__ __launch_bounds__(256) void k_main(const float4* __restrict__ gt,
                                              const float4* __restrict__ anc,
                                              float* __restrict__ out,
                                              uint32_t* __restrict__ w,
                                              uint32_t* __restrict__ rnk,
                                              uint32_t* __restrict__ seg) {
#pragma clang fp contract(off)
    const int b = blockIdx.y;
    const int n = blockIdx.x * 256 + threadIdx.x;
    const int t = threadIdx.x;

    __shared__ float4 sgv[NG];    // (gx0, gy0, gx1, gy1)
    __shared__ float  sgar[NG];   // gt area
    __shared__ float4 sg0[NG];    // batch-0 boxes (reference gt_flat indexing bug)
    __shared__ float  sout[256 * 5];
    __shared__ uint32_t sred[4];  // per-wave packed (pos<<16 | neg)
    __shared__ uint32_t shist[256];  // coarse (top-8-bit) rank-key hist, label-0
    shist[t] = 0;
    if (t < NG) {
        float4 g = gt[b * NG + t];
        sgv[t] = make_float4(g.x, g.y, g.x + g.z, g.y + g.w);
        sgar[t] = g.z * g.w;
    } else if (t < 2 * NG) {
        sg0[t - NG] = gt[t - NG];
    }
    __syncthreads();

    float4 a = anc[n];
    float ax1 = a.x + a.z;
    float ay1 = a.y + a.w;
    float aar = a.z * a.w;
    bool keep = (a.x >= 0.f) && (a.y >= 0.f) && (a.z >= 0.f) && (a.w >= 0.f)
             && (a.x <= 63.f) && (a.y <= 63.f)
             && ((ax1 - 1.0f) <= 63.f) && ((ay1 - 1.0f) <= 63.f);

    float nb_ = 1e-10f, db_ = 1.0f;   // best fraction
    int ib_ = 0;
    // Whole-wave skip: !keep anchors' IoU never reaches the output (label -1,
    // targets 0, not counted, not ranked). ~12% of waves are fully !keep
    // (border rows for tall anchor types).
    if (__ballot(keep) != 0ull) {
        {
            float4 gv = sgv[0];
            float iw = fmaxf(0.0f, fminf(ax1, gv.z) - fmaxf(a.x, gv.x));
            float ih = fmaxf(0.0f, fminf(ay1, gv.w) - fmaxf(a.y, gv.y));
            float inter = iw * ih;
            float uni = (aar + sgar[0]) - inter;
            nb_ = inter; db_ = uni;
            if (inter == 0.0f) { nb_ = 1e-10f; db_ = 1.0f; }
        }
#pragma unroll 4
        for (int g = 1; g < NG; ++g) {
            float4 gv = sgv[g];
            float iw = fmaxf(0.0f, fminf(ax1, gv.z) - fmaxf(a.x, gv.x));
            float ih = fmaxf(0.0f, fminf(ay1, gv.w) - fmaxf(a.y, gv.y));
            float inter = iw * ih;
            float uni = (aar + sgar[g]) - inter;
            float ng_ = inter, dg_ = uni;
            if (inter == 0.0f) { ng_ = 1e-10f; dg_ = 1.0f; }

            float p = ng_ * db_;
            float q = nb_ * dg_;
            float d_ = p - q;
            float band = 0x1p-20f * fmaxf(p, q);
            bool same = (ng_ == nb_) && (dg_ == db_);
            bool nearby = (!same) && (fabsf(d_) <= band);
            bool win;
            if (__builtin_expect(nearby, 0)) {
                float ovg = ng_ / dg_;
                float ovb = nb_ / db_;
                win = ovg > ovb;                    // rounded compare, tie keeps earlier
            } else {
                win = d_ > band;                    // same => d_==0 => false (keep earlier)
            }
            if (win) { nb_ = ng_; db_ = dg_; ib_ = g; }
        }
    }
    float best = nb_ / db_;    // == reference max_ov, bit-exact

    float label = -1.0f;
    if (keep) label = (best >= 0.7f) ? 1.0f : ((best <= 0.3f) ? 0.0f : -1.0f);

    // pos/neg: ballot + LDS combine + one plain store per block (R3 win).
    uint64_t bp = __ballot(keep && (best > 0.7f));   // pos (strict >)
    uint64_t bn = __ballot(keep && (best < 0.3f));   // neg (strict <)
    if ((t & 63) == 0)
        sred[t >> 6] = ((uint32_t)__popcll(bp) << 16) | (uint32_t)__popcll(bn);

    float t0 = 0.f, t1 = 0.f, t2 = 0.f, t3 = 0.f;
    if (keep) {
        float4 g0 = sg0[ib_];                 // always batch-0 (ref bug)
        t0 = a.x - g0.x / 16.0f;
        t1 = a.y - g0.y / 16.0f;
        t2 = a.z - g0.z / 16.0f;
        t3 = a.w - g0.w / 16.0f;
    }

    // Stage to LDS (stride 5, coprime with 32 banks), then coalesced stores.
    sout[t * 5 + 0] = label;
    sout[t * 5 + 1] = t0; sout[t * 5 + 2] = t1;
    sout[t * 5 + 3] = t2; sout[t * 5 + 4] = t3;

    uint32_t idx = (uint32_t)(b * NN + n);
    uint32_t u = threefry_bits(idx) >> 9;     // 23-bit rank key
    if (label == 0.0f) {
        uint32_t bin = u >> 15;
        uint32_t slot = atomicAdd(&shist[bin], 1u);   // free deterministic-set slot
        if (slot < SEGC)
            seg[(((uint32_t)b * 256 + bin) * NBLK + (uint32_t)blockIdx.x) * SEGC + slot]
                = (u << 8) | ((uint32_t)t & 255u);    // (u23 | local_n8)
    }
    uint32_t lab2 = (label == 0.0f) ? 2u : ((label == 1.0f) ? 1u : 0u);
    rnk[idx] = (u << 2) | lab2;

    __syncthreads();
    if (t == 0)
        w[WS_PART + b * NBLK + blockIdx.x] = sred[0] + sred[1] + sred[2] + sred[3];
    // Transposed tile-hist store: [b][word t][tile] (R6 win).
    if (t < 128)
        w[WS_BH + (b * 128 + t) * NBLK + blockIdx.x] =
            (shist[2 * t] & 0xFFFFu) | (shist[2 * t + 1] << 16);
    float* ob = out + ((size_t)b * NN + (size_t)blockIdx.x * 256) * 5;
#pragma unroll
    for (int k = 0; k < 5; ++k) ob[k * 256 + t] = sout[k * 256 + t];
}

// Grid = (NCH, NB) = 1024 blocks. Each block redundantly computes row stats
// (deterministic), gathers boundary-bin entries from SEGMENTS (no full-row
// scan — the R6 45us wall), then disables only its own CHSZ-anchor chunk.
__global__ __launch_bounds__(256) void k_post(float* __restrict__ out,
                                              const uint32_t* __restrict__ w,
                                              const uint32_t* __restrict__ rnk,
                                              const uint32_t* __restrict__ seg) {
    const int b = blockIdx.y;
    const int ch = blockIdx.x;
    const int t = threadIdx.x;
    __shared__ uint32_t rp[256], rn[256];
    __shared__ uint32_t sph[256];           // packed per-thread hist partials
    __shared__ uint32_t hcnt[256];          // row coarse hist
    __shared__ uint32_t lu[CAP], li[CAP];   // boundary-bin entries (row-wide)
    __shared__ uint32_t scnt;
    __shared__ int sC;
    __shared__ uint32_t sBase;
    if (t == 0) scnt = 0;

    // 1. pos/neg from the 3072 packed partials (uint4 loads).
    uint32_t sp = 0, sn = 0;
    {
        const uint4* p4 = (const uint4*)(w + WS_PART);
#pragma unroll
        for (int k = 0; k < 3; ++k) {
            uint4 v = p4[t + k * 256];
            sp += (v.x >> 16) + (v.y >> 16) + (v.z >> 16) + (v.w >> 16);
            sn += (v.x & 0xFFFFu) + (v.y & 0xFFFFu) + (v.z & 0xFFFFu) + (v.w & 0xFFFFu);
        }
    }
    rp[t] = sp; rn[t] = sn;
    __syncthreads();
    for (int s = 128; s > 0; s >>= 1) {
        if (t < s) { rp[t] += rp[t + s]; rn[t] += rn[t + s]; }
        __syncthreads();
    }
    uint32_t pos = rp[0], neg = rn[0];
    uint32_t cutoff = 3u * pos; if (cutoff < 1u) cutoff = 1u;
    if (neg <= cutoff) return;     // uniform across grid: no disabling at all

    // 2. row coarse hist from transposed tile hists (contiguous uint4 runs).
    {
        int d = t >> 1, half = t & 1;
        const uint4* h4 = (const uint4*)(w + WS_BH + (b * 128 + d) * NBLK + half * 96);
        uint32_t c = 0;
#pragma unroll 4
        for (int k = 0; k < 24; ++k) {
            uint4 v = h4[k];
            c += v.x + v.y + v.z + v.w;
        }
        sph[t] = c;
    }
    __syncthreads();
    if (t < 128) {
        uint32_t v0 = sph[2 * t], v1 = sph[2 * t + 1];
        hcnt[2 * t]     = (v0 & 0xFFFFu) + (v1 & 0xFFFFu);
        hcnt[2 * t + 1] = (v0 >> 16) + (v1 >> 16);
    }
    __syncthreads();

    // 3. top-down scan over 256 coarse bins -> boundary bin C, base rank.
    if (t == 0) {
        uint32_t cum = 0; int C = -1; uint32_t base = 0;
        for (int c = 255; c >= 0; --c) {
            if (cum + hcnt[c] >= cutoff) { C = c; base = cum; break; }
            cum += hcnt[c];
        }
        sC = C; sBase = base;
    }
    __syncthreads();
    int C = sC;
    if (C < 0) return;             // row has < cutoff label-0 -> keep all

    // 4a. gather bin-C entries from segments: thread t<192 handles tile t.
    if (t < NBLK) {
        uint32_t cw = w[WS_BH + (b * 128 + (C >> 1)) * NBLK + t];
        uint32_t cnt_t = (C & 1) ? (cw >> 16) : (cw & 0xFFFFu);
        if (cnt_t <= SEGC) {
            const uint32_t* sg = seg +
                (((uint32_t)b * 256 + (uint32_t)C) * NBLK + (uint32_t)t) * SEGC;
            for (uint32_t k = 0; k < cnt_t; ++k) {
                uint32_t v = sg[k];
                uint32_t p_ = atomicAdd(&scnt, 1u);
                if (p_ < CAP) { lu[p_] = v >> 8; li[p_] = (uint32_t)t * 256u + (v & 255u); }
            }
        } else {
            // overflow (P ~ 1e-8): scan this tile's 256 rnk words directly.
            const uint32_t* rr = rnk + (size_t)b * NN + (size_t)t * 256;
            for (int k = 0; k < 256; ++k) {
                uint32_t val = rr[k];
                if ((val & 3u) == 2u && (int)((val >> 2) >> 15) == C) {
                    uint32_t p_ = atomicAdd(&scnt, 1u);
                    if (p_ < CAP) { lu[p_] = val >> 2; li[p_] = (uint32_t)t * 256u + (uint32_t)k; }
                }
            }
        }
    }

    // 4b. own chunk: coarse bin < C -> disabled (768 anchors, uint4 reads).
    {
        const uint4* r4 = (const uint4*)(rnk + (size_t)b * NN + (size_t)ch * CHSZ);
        if (t < CHSZ / 4) {
            uint4 v = r4[t];
            uint32_t vv[4] = {v.x, v.y, v.z, v.w};
#pragma unroll
            for (int k = 0; k < 4; ++k) {
                uint32_t val = vv[k];
                if ((val & 3u) == 2u && (int)((val >> 2) >> 15) < C) {
                    int i = ch * CHSZ + t * 4 + k;
                    out[((size_t)b * NN + i) * 5] = -1.0f;
                }
            }
        }
    }
    __syncthreads();

    // 5. exact rank resolution for boundary entries in MY chunk.
    uint32_t cnt = scnt; if (cnt > CAP) cnt = CAP;
    uint32_t baseRank = sBase;
    for (uint32_t k = t; k < cnt; k += 256) {
        uint32_t u = lu[k], n = li[k];
        if (n / (uint32_t)CHSZ != (uint32_t)ch) continue;
        uint32_t r = baseRank;
        for (uint32_t j = 0; j < cnt; ++j) {
            // descending u, ties by smaller index first (stable argsort)
            r += (lu[j] > u || (lu[j] == u && li[j] < n)) ? 1u : 0u;
        }
        if (r >= cutoff) out[((size_t)b * NN + n) * 5] = -1.0f;
    }
}

// Fallback post kernel (R6 structure) if ws is too small for segments.
__global__ __launch_bounds__(256) void k_post_slow(float* __restrict__ out,
                                                   const uint32_t* __restrict__ w) {
    const int b = blockIdx.y;
    const int ch = blockIdx.x;
    const int t = threadIdx.x;
    __shared__ uint32_t rp[256], rn[256];
    __shared__ uint32_t sph[256];
    __shared__ uint32_t hcnt[256];
    __shared__ uint32_t lu[CAP], li[CAP];
    __shared__ uint32_t scnt;
    __shared__ int sC;
    __shared__ uint32_t sBase;
    if (t == 0) scnt = 0;
    uint32_t sp = 0, sn = 0;
    {
        const uint4* p4 = (const uint4*)(w + WS_PART);
#pragma unroll
        for (int k = 0; k < 3; ++k) {
            uint4 v = p4[t + k * 256];
            sp += (v.x >> 16) + (v.y >> 16) + (v.z >> 16) + (v.w >> 16);
            sn += (v.x & 0xFFFFu) + (v.y & 0xFFFFu) + (v.z & 0xFFFFu) + (v.w & 0xFFFFu);
        }
    }
    rp[t] = sp; rn[t] = sn;
    __syncthreads();
    for (int s = 128; s > 0; s >>= 1) {
        if (t < s) { rp[t] += rp[t + s]; rn[t] += rn[t + s]; }
        __syncthreads();
    }
    uint32_t pos = rp[0], neg = rn[0];
    uint32_t cutoff = 3u * pos; if (cutoff < 1u) cutoff = 1u;
    if (neg <= cutoff) return;
    {
        int d = t >> 1, half = t & 1;
        const uint4* h4 = (const uint4*)(w + WS_BH + (b * 128 + d) * NBLK + half * 96);
        uint32_t c = 0;
#pragma unroll 4
        for (int k = 0; k < 24; ++k) { uint4 v = h4[k]; c += v.x + v.y + v.z + v.w; }
        sph[t] = c;
    }
    __syncthreads();
    if (t < 128) {
        uint32_t v0 = sph[2 * t], v1 = sph[2 * t + 1];
        hcnt[2 * t]     = (v0 & 0xFFFFu) + (v1 & 0xFFFFu);
        hcnt[2 * t + 1] = (v0 >> 16) + (v1 >> 16);
    }
    __syncthreads();
    if (t == 0) {
        uint32_t cum = 0; int C = -1; uint32_t base = 0;
        for (int c = 255; c >= 0; --c) {
            if (cum + hcnt[c] >= cutoff) { C = c; base = cum; break; }
            cum += hcnt[c];
        }
        sC = C; sBase = base;
    }
    __syncthreads();
    int C = sC;
    if (C < 0) return;
    for (int i = t; i < NN; i += 256) {
        uint32_t idx = (uint32_t)(b * NN + i);
        if (out[(size_t)idx * 5] == 0.0f) {
            uint32_t u = threefry_bits(idx) >> 9;
            if ((int)(u >> 15) == C) {
                uint32_t p_ = atomicAdd(&scnt, 1u);
                if (p_ < CAP) { lu[p_] = u; li[p_] = (uint32_t)i; }
            }
        }
    }
    for (int i2 = t; i2 < CHSZ; i2 += 256) {
        int i = ch * CHSZ + i2;
        uint32_t idx = (uint32_t)(b * NN + i);
        if (out[(size_t)idx * 5] == 0.0f) {
            uint32_t u = threefry_bits(idx) >> 9;
            if ((int)(u >> 15) < C) out[(size_t)idx * 5] = -1.0f;
        }
    }
    __syncthreads();
    uint32_t cnt = scnt; if (cnt > CAP) cnt = CAP;
    uint32_t baseRank = sBase;
    for (uint32_t k = t; k < cnt; k += 256) {
        uint32_t u = lu[k], n = li[k];
        if (n / (uint32_t)CHSZ != (uint32_t)ch) continue;
        uint32_t r = baseRank;
        for (uint32_t j = 0; j < cnt; ++j)
            r += (lu[j] > u || (lu[j] == u && li[j] < n)) ? 1u : 0u;
        if (r >= cutoff) out[((size_t)b * NN + n) * 5] = -1.0f;
    }
}

// Minimal k_main companion for the no-segment fallback (writes labels only
// through out; k_post_slow recomputes threefry). Reuses k_main with seg=null
// guarded inside — simpler: pass a dummy; see launch.

extern "C" void kernel_launch(void* const* d_in, const int* in_sizes, int n_in,
                              void* d_out, int out_size, void* d_ws, size_t ws_size,
                              hipStream_t stream) {
    // d_in[0] = cls_scores (shape-relevant only, never read)
    const float4* gt  = (const float4*)d_in[1];
    const float4* anc = (const float4*)d_in[2];
    float* out = (float*)d_out;
    uint32_t* w = (uint32_t*)d_ws;
    bool big = (ws_size >= WS_NEED_ALL);
    uint32_t* rnk = w + WS_RNK;
    uint32_t* seg = w + WS_SEG;

    if (big) {
        k_main<<<dim3(NBLK, NB), 256, 0, stream>>>(gt, anc, out, w, rnk, seg);
        k_post<<<dim3(NCH, NB), 256, 0, stream>>>(out, w, rnk, seg);
    } else {
        // Small-ws fallback: still need rnk-free path; reuse k_main writing
        // rnk/seg only if they fit, else degrade gracefully.
        if (ws_size >= ((size_t)WS_SEG) * 4) {
            k_main<<<dim3(NBLK, NB), 256, 0, stream>>>(gt, anc, out, w, rnk, rnk /*seg unused but valid*/);
        } else {
            // ws must at least hold partials+hists (~1.6 MB): guaranteed by
            // harness sizing in practice.
            k_main<<<dim3(NBLK, NB), 256, 0, stream>>>(gt, anc, out, w, w + WS_PART, w + WS_PART);
        }
        k_post_slow<<<dim3(NCH, NB), 256, 0, stream>>>(out, w);
    }
}

// Round 8
// 110.743 us; speedup vs baseline: 1.6750x; 1.1116x over previous
//
#include <hip/hip_runtime.h>
#include <stdint.h>

// Bit-exact f32 vs numpy reference required for label thresholds:
// kill FMA contraction everywhere.
#pragma clang fp contract(off)

#define NB 16       // batch
#define NA 12       // anchors per cell
#define NH 64
#define NW 64
#define NG 64       // gt boxes per batch
#define NN (NA*NH*NW)   // 49152 anchors per batch row
#define NBLK (NN/256)   // 192 k_main tiles per batch row
#define NCH 64          // k_post chunks per row (64 x 16 = 1024 blocks)
#define CHSZ (NN/NCH)   // 768 anchors per k_post block
#define CAP 2048        // boundary-bin LDS list capacity (expected ~137)
#define SEGC 8          // segment capacity per (row,bin,tile)

// ws layout (uint32 index) — nothing needs pre-zeroing (counts for segments
// come from the tile hists; harness poisons ws with 0xAA every launch):
// [0 .. 3072)                      per-tile packed (pos<<16|neg) partials
// [4096 ..)                        tile hists, TRANSPOSED [b][word d][tile],
//                                  word d packs bins (2d,2d+1) as u16 pair
// [WS_RNK ..)                      rnk32 = (u23<<2)|lab2 per anchor
// [WS_SEG ..)                      segments [b][bin][tile][slot<SEGC]:
//                                  entry = (u23<<8) | local_n8  (31 bits)
#define WS_PART 0
#define WS_BH   4096
#define WS_RNK  (WS_BH + NB*128*NBLK)                  // 397312
#define WS_SEG  (WS_RNK + NB*NN)                       // 1183744
#define WS_NEED_ALL (((size_t)WS_SEG + (size_t)NB*256*NBLK*SEGC) * 4)  // ~30 MB

__device__ __forceinline__ uint32_t rotl32(uint32_t x, int r) {
    return (x << r) | (x >> (32 - r));
}

// threefry2x32, key = jax.random.key(42) -> (0, 42), partitionable counters:
// x0 = hi(flat_idx)=0, x1 = lo(flat_idx)=i; 32-bit draw = out0 ^ out1.
// Verified bit-exact (absmax 0 in R1-R7).
__device__ uint32_t threefry_bits(uint32_t idx) {
    const uint32_t ks0 = 0u, ks1 = 42u, ks2 = 0x1BD11BDAu ^ 0u ^ 42u;
    uint32_t x0 = ks0;
    uint32_t x1 = idx + ks1;
#define RND(r) { x0 += x1; x1 = rotl32(x1, r); x1 ^= x0; }
    RND(13) RND(15) RND(26) RND(6)
    x0 += ks1; x1 += ks2 + 1u;
    RND(17) RND(29) RND(16) RND(24)
    x0 += ks2; x1 += ks0 + 2u;
    RND(13) RND(15) RND(26) RND(6)
    x0 += ks0; x1 += ks1 + 3u;
    RND(17) RND(29) RND(16) RND(24)
    x0 += ks1; x1 += ks2 + 4u;
    RND(13) RND(15) RND(26) RND(6)
    x0 += ks2; x1 += ks0 + 5u;
#undef RND
    return x0 ^ x1;
}

// Division-free argmax (verified bit-exact R1-R7) + NEW wave-uniform y-prune:
// within a wave, anchor y0/h are constant (n spans j=0..63 at fixed (a,i)),
// so boxes with no y-overlap give ov == 1e-10 for every lane — exactly the
// substituted value, which can never win the running max (best >= 1e-10,
// ties keep earlier). One __ballot builds the candidate mask (~15/64 set).
__global__ __launch_bounds__(256) void k_main(const float4* __restrict__ gt,
                                              const float4* __restrict__ anc,
                                              float* __restrict__ out,
                                              uint32_t* __restrict__ w,
                                              uint32_t* __restrict__ rnk,
                                              uint32_t* __restrict__ seg) {
#pragma clang fp contract(off)
    const int b = blockIdx.y;
    const int n = blockIdx.x * 256 + threadIdx.x;
    const int t = threadIdx.x;

    __shared__ float4 sgv[NG];    // (gx0, gy0, gx1, gy1)
    __shared__ float  sgar[NG];   // gt area
    __shared__ float4 sg0[NG];    // batch-0 boxes (reference gt_flat indexing bug)
    __shared__ float  sout[256 * 5];
    __shared__ uint32_t sred[4];  // per-wave packed (pos<<16 | neg)
    __shared__ uint32_t shist[256];  // coarse (top-8-bit) rank-key hist, label-0
    shist[t] = 0;
    if (t < NG) {
        float4 g = gt[b * NG + t];
        sgv[t] = make_float4(g.x, g.y, g.x + g.z, g.y + g.w);
        sgar[t] = g.z * g.w;
    } else if (t < 2 * NG) {
        sg0[t - NG] = gt[t - NG];
    }
    __syncthreads();

    float4 a = anc[n];
    float ax1 = a.x + a.z;
    float ay1 = a.y + a.w;
    float aar = a.z * a.w;
    bool keep = (a.x >= 0.f) && (a.y >= 0.f) && (a.z >= 0.f) && (a.w >= 0.f)
             && (a.x <= 63.f) && (a.y <= 63.f)
             && ((ax1 - 1.0f) <= 63.f) && ((ay1 - 1.0f) <= 63.f);

    float nb_ = 1e-10f, db_ = 1.0f;   // best fraction (virtual init = 1e-10/1)
    int ib_ = 0;
    if (__ballot(keep) != 0ull) {     // whole-wave skip (~12% of waves)
        // Wave-uniform y-overlap mask: lane L tests box L (a.y, ay1 uniform).
        int lane = t & 63;
        float4 gl = sgv[lane];
        float rih = fminf(ay1, gl.w) - fmaxf(a.y, gl.y);
        uint64_t M = __ballot(rih > 0.0f);

        bool tookwin = false;
        int minEmpty = 64;            // first evaluated candidate with inter==0
        uint64_t m = M;
        while (m) {
            int g = (int)__builtin_ctzll(m); m &= m - 1;
            float4 gv = sgv[g];
            float iw = fmaxf(0.0f, fminf(ax1, gv.z) - fmaxf(a.x, gv.x));
            float ih = fmaxf(0.0f, fminf(ay1, gv.w) - fmaxf(a.y, gv.y));
            float inter = iw * ih;
            if (inter == 0.0f) {      // value == 1e-10 exactly: can never win
                if (g < minEmpty) minEmpty = g;
                continue;
            }
            float uni = (aar + sgar[g]) - inter;
            float p = inter * db_;
            float q = nb_ * uni;
            float d_ = p - q;
            float band = 0x1p-20f * fmaxf(p, q);
            bool win;
            if (__builtin_expect(fabsf(d_) <= band, 0)) {
                float ovg = inter / uni;
                float ovb = nb_ / db_;
                win = ovg > ovb;      // rounded compare; ties keep earlier
            } else {
                win = d_ > band;      // provable rounded ordering outside band
            }
            if (win) { nb_ = inter; db_ = uni; ib_ = g; tookwin = true; }
        }
        if (!tookwin) {
            // best is exactly 1e-10: reference argmax = first g with ov==1e-10
            // = min(first non-candidate, first evaluated-empty).
            uint64_t notM = ~M;
            int firstNon = notM ? (int)__builtin_ctzll(notM) : 64;
            int e = firstNon < minEmpty ? firstNon : minEmpty;
            if (__builtin_expect(e >= 64, 0)) {
                // measure-zero guard: all 64 genuine yet none beat 1e-10
                // (needs ov < 1e-10 on every box). Full reference loop.
                {
                    float4 gv = sgv[0];
                    float iw = fmaxf(0.0f, fminf(ax1, gv.z) - fmaxf(a.x, gv.x));
                    float ih = fmaxf(0.0f, fminf(ay1, gv.w) - fmaxf(a.y, gv.y));
                    float inter = iw * ih;
                    float uni = (aar + sgar[0]) - inter;
                    nb_ = inter; db_ = uni; ib_ = 0;
                    if (inter == 0.0f) { nb_ = 1e-10f; db_ = 1.0f; }
                }
                for (int g = 1; g < NG; ++g) {
                    float4 gv = sgv[g];
                    float iw = fmaxf(0.0f, fminf(ax1, gv.z) - fmaxf(a.x, gv.x));
                    float ih = fmaxf(0.0f, fminf(ay1, gv.w) - fmaxf(a.y, gv.y));
                    float inter = iw * ih;
                    float uni = (aar + sgar[g]) - inter;
                    float ng_ = inter, dg_ = uni;
                    if (inter == 0.0f) { ng_ = 1e-10f; dg_ = 1.0f; }
                    float p = ng_ * db_;
                    float q = nb_ * dg_;
                    float d_ = p - q;
                    float band = 0x1p-20f * fmaxf(p, q);
                    bool same = (ng_ == nb_) && (dg_ == db_);
                    bool win;
                    if (!same && fabsf(d_) <= band) {
                        win = (ng_ / dg_) > (nb_ / db_);
                    } else {
                        win = d_ > band;
                    }
                    if (win) { nb_ = ng_; db_ = dg_; ib_ = g; }
                }
            } else {
                ib_ = e;
            }
        }
    }
    float best = nb_ / db_;    // == reference max_ov, bit-exact

    float label = -1.0f;
    if (keep) label = (best >= 0.7f) ? 1.0f : ((best <= 0.3f) ? 0.0f : -1.0f);

    // pos/neg: ballot + LDS combine + one plain store per block (R3 win).
    uint64_t bp = __ballot(keep && (best > 0.7f));   // pos (strict >)
    uint64_t bn = __ballot(keep && (best < 0.3f));   // neg (strict <)
    if ((t & 63) == 0)
        sred[t >> 6] = ((uint32_t)__popcll(bp) << 16) | (uint32_t)__popcll(bn);

    float t0 = 0.f, t1 = 0.f, t2 = 0.f, t3 = 0.f;
    if (keep) {
        float4 g0 = sg0[ib_];                 // always batch-0 (ref bug)
        t0 = a.x - g0.x / 16.0f;
        t1 = a.y - g0.y / 16.0f;
        t2 = a.z - g0.z / 16.0f;
        t3 = a.w - g0.w / 16.0f;
    }

    // Stage to LDS (stride 5, coprime with 32 banks), then coalesced stores.
    sout[t * 5 + 0] = label;
    sout[t * 5 + 1] = t0; sout[t * 5 + 2] = t1;
    sout[t * 5 + 3] = t2; sout[t * 5 + 4] = t3;

    uint32_t idx = (uint32_t)(b * NN + n);
    uint32_t u = threefry_bits(idx) >> 9;     // 23-bit rank key
    if (label == 0.0f) {
        uint32_t bin = u >> 15;
        uint32_t slot = atomicAdd(&shist[bin], 1u);   // free deterministic-set slot
        if (slot < SEGC)
            seg[(((uint32_t)b * 256 + bin) * NBLK + (uint32_t)blockIdx.x) * SEGC + slot]
                = (u << 8) | ((uint32_t)t & 255u);    // (u23 | local_n8)
    }
    uint32_t lab2 = (label == 0.0f) ? 2u : ((label == 1.0f) ? 1u : 0u);
    rnk[idx] = (u << 2) | lab2;

    __syncthreads();
    if (t == 0)
        w[WS_PART + b * NBLK + blockIdx.x] = sred[0] + sred[1] + sred[2] + sred[3];
    // Transposed tile-hist store: [b][word t][tile] (R6 win).
    if (t < 128)
        w[WS_BH + (b * 128 + t) * NBLK + blockIdx.x] =
            (shist[2 * t] & 0xFFFFu) | (shist[2 * t + 1] << 16);
    float* ob = out + ((size_t)b * NN + (size_t)blockIdx.x * 256) * 5;
#pragma unroll
    for (int k = 0; k < 5; ++k) ob[k * 256 + t] = sout[k * 256 + t];
}

// Grid = (NCH, NB) = 1024 blocks. Each block redundantly computes row stats
// (deterministic), gathers boundary-bin entries from SEGMENTS (R7 win),
// then disables only its own CHSZ-anchor chunk.
__global__ __launch_bounds__(256) void k_post(float* __restrict__ out,
                                              const uint32_t* __restrict__ w,
                                              const uint32_t* __restrict__ rnk,
                                              const uint32_t* __restrict__ seg) {
    const int b = blockIdx.y;
    const int ch = blockIdx.x;
    const int t = threadIdx.x;
    __shared__ uint32_t rp[256], rn[256];
    __shared__ uint32_t sph[256];           // packed per-thread hist partials
    __shared__ uint32_t hcnt[256];          // row coarse hist
    __shared__ uint32_t lu[CAP], li[CAP];   // boundary-bin entries (row-wide)
    __shared__ uint32_t scnt;
    __shared__ int sC;
    __shared__ uint32_t sBase;
    if (t == 0) scnt = 0;

    // 1. pos/neg from the 3072 packed partials (uint4 loads).
    uint32_t sp = 0, sn = 0;
    {
        const uint4* p4 = (const uint4*)(w + WS_PART);
#pragma unroll
        for (int k = 0; k < 3; ++k) {
            uint4 v = p4[t + k * 256];
            sp += (v.x >> 16) + (v.y >> 16) + (v.z >> 16) + (v.w >> 16);
            sn += (v.x & 0xFFFFu) + (v.y & 0xFFFFu) + (v.z & 0xFFFFu) + (v.w & 0xFFFFu);
        }
    }
    rp[t] = sp; rn[t] = sn;
    __syncthreads();
    for (int s = 128; s > 0; s >>= 1) {
        if (t < s) { rp[t] += rp[t + s]; rn[t] += rn[t + s]; }
        __syncthreads();
    }
    uint32_t pos = rp[0], neg = rn[0];
    uint32_t cutoff = 3u * pos; if (cutoff < 1u) cutoff = 1u;
    if (neg <= cutoff) return;     // uniform across grid: no disabling at all

    // 2. row coarse hist from transposed tile hists (contiguous uint4 runs).
    {
        int d = t >> 1, half = t & 1;
        const uint4* h4 = (const uint4*)(w + WS_BH + (b * 128 + d) * NBLK + half * 96);
        uint32_t c = 0;
#pragma unroll 4
        for (int k = 0; k < 24; ++k) {
            uint4 v = h4[k];
            c += v.x + v.y + v.z + v.w;
        }
        sph[t] = c;
    }
    __syncthreads();
    if (t < 128) {
        uint32_t v0 = sph[2 * t], v1 = sph[2 * t + 1];
        hcnt[2 * t]     = (v0 & 0xFFFFu) + (v1 & 0xFFFFu);
        hcnt[2 * t + 1] = (v0 >> 16) + (v1 >> 16);
    }
    __syncthreads();

    // 3. top-down scan over 256 coarse bins -> boundary bin C, base rank.
    if (t == 0) {
        uint32_t cum = 0; int C = -1; uint32_t base = 0;
        for (int c = 255; c >= 0; --c) {
            if (cum + hcnt[c] >= cutoff) { C = c; base = cum; break; }
            cum += hcnt[c];
        }
        sC = C; sBase = base;
    }
    __syncthreads();
    int C = sC;
    if (C < 0) return;             // row has < cutoff label-0 -> keep all

    // 4a. gather bin-C entries from segments: thread t<192 handles tile t.
    if (t < NBLK) {
        uint32_t cw = w[WS_BH + (b * 128 + (C >> 1)) * NBLK + t];
        uint32_t cnt_t = (C & 1) ? (cw >> 16) : (cw & 0xFFFFu);
        if (cnt_t <= SEGC) {
            const uint32_t* sg = seg +
                (((uint32_t)b * 256 + (uint32_t)C) * NBLK + (uint32_t)t) * SEGC;
            for (uint32_t k = 0; k < cnt_t; ++k) {
                uint32_t v = sg[k];
                uint32_t p_ = atomicAdd(&scnt, 1u);
                if (p_ < CAP) { lu[p_] = v >> 8; li[p_] = (uint32_t)t * 256u + (v & 255u); }
            }
        } else {
            // overflow (P ~ 1e-8): scan this tile's 256 rnk words directly.
            const uint32_t* rr = rnk + (size_t)b * NN + (size_t)t * 256;
            for (int k = 0; k < 256; ++k) {
                uint32_t val = rr[k];
                if ((val & 3u) == 2u && (int)((val >> 2) >> 15) == C) {
                    uint32_t p_ = atomicAdd(&scnt, 1u);
                    if (p_ < CAP) { lu[p_] = val >> 2; li[p_] = (uint32_t)t * 256u + (uint32_t)k; }
                }
            }
        }
    }

    // 4b. own chunk: coarse bin < C -> disabled (768 anchors, uint4 reads).
    {
        const uint4* r4 = (const uint4*)(rnk + (size_t)b * NN + (size_t)ch * CHSZ);
        if (t < CHSZ / 4) {
            uint4 v = r4[t];
            uint32_t vv[4] = {v.x, v.y, v.z, v.w};
#pragma unroll
            for (int k = 0; k < 4; ++k) {
                uint32_t val = vv[k];
                if ((val & 3u) == 2u && (int)((val >> 2) >> 15) < C) {
                    int i = ch * CHSZ + t * 4 + k;
                    out[((size_t)b * NN + i) * 5] = -1.0f;
                }
            }
        }
    }
    __syncthreads();

    // 5. exact rank resolution for boundary entries in MY chunk.
    uint32_t cnt = scnt; if (cnt > CAP) cnt = CAP;
    uint32_t baseRank = sBase;
    for (uint32_t k = t; k < cnt; k += 256) {
        uint32_t u = lu[k], n = li[k];
        if (n / (uint32_t)CHSZ != (uint32_t)ch) continue;
        uint32_t r = baseRank;
        for (uint32_t j = 0; j < cnt; ++j) {
            // descending u, ties by smaller index first (stable argsort)
            r += (lu[j] > u || (lu[j] == u && li[j] < n)) ? 1u : 0u;
        }
        if (r >= cutoff) out[((size_t)b * NN + n) * 5] = -1.0f;
    }
}

// Fallback post kernel (R6 structure) if ws is too small for segments.
__global__ __launch_bounds__(256) void k_post_slow(float* __restrict__ out,
                                                   const uint32_t* __restrict__ w) {
    const int b = blockIdx.y;
    const int ch = blockIdx.x;
    const int t = threadIdx.x;
    __shared__ uint32_t rp[256], rn[256];
    __shared__ uint32_t sph[256];
    __shared__ uint32_t hcnt[256];
    __shared__ uint32_t lu[CAP], li[CAP];
    __shared__ uint32_t scnt;
    __shared__ int sC;
    __shared__ uint32_t sBase;
    if (t == 0) scnt = 0;
    uint32_t sp = 0, sn = 0;
    {
        const uint4* p4 = (const uint4*)(w + WS_PART);
#pragma unroll
        for (int k = 0; k < 3; ++k) {
            uint4 v = p4[t + k * 256];
            sp += (v.x >> 16) + (v.y >> 16) + (v.z >> 16) + (v.w >> 16);
            sn += (v.x & 0xFFFFu) + (v.y & 0xFFFFu) + (v.z & 0xFFFFu) + (v.w & 0xFFFFu);
        }
    }
    rp[t] = sp; rn[t] = sn;
    __syncthreads();
    for (int s = 128; s > 0; s >>= 1) {
        if (t < s) { rp[t] += rp[t + s]; rn[t] += rn[t + s]; }
        __syncthreads();
    }
    uint32_t pos = rp[0], neg = rn[0];
    uint32_t cutoff = 3u * pos; if (cutoff < 1u) cutoff = 1u;
    if (neg <= cutoff) return;
    {
        int d = t >> 1, half = t & 1;
        const uint4* h4 = (const uint4*)(w + WS_BH + (b * 128 + d) * NBLK + half * 96);
        uint32_t c = 0;
#pragma unroll 4
        for (int k = 0; k < 24; ++k) { uint4 v = h4[k]; c += v.x + v.y + v.z + v.w; }
        sph[t] = c;
    }
    __syncthreads();
    if (t < 128) {
        uint32_t v0 = sph[2 * t], v1 = sph[2 * t + 1];
        hcnt[2 * t]     = (v0 & 0xFFFFu) + (v1 & 0xFFFFu);
        hcnt[2 * t + 1] = (v0 >> 16) + (v1 >> 16);
    }
    __syncthreads();
    if (t == 0) {
        uint32_t cum = 0; int C = -1; uint32_t base = 0;
        for (int c = 255; c >= 0; --c) {
            if (cum + hcnt[c] >= cutoff) { C = c; base = cum; break; }
            cum += hcnt[c];
        }
        sC = C; sBase = base;
    }
    __syncthreads();
    int C = sC;
    if (C < 0) return;
    for (int i = t; i < NN; i += 256) {
        uint32_t idx = (uint32_t)(b * NN + i);
        if (out[(size_t)idx * 5] == 0.0f) {
            uint32_t u = threefry_bits(idx) >> 9;
            if ((int)(u >> 15) == C) {
                uint32_t p_ = atomicAdd(&scnt, 1u);
                if (p_ < CAP) { lu[p_] = u; li[p_] = (uint32_t)i; }
            }
        }
    }
    for (int i2 = t; i2 < CHSZ; i2 += 256) {
        int i = ch * CHSZ + i2;
        uint32_t idx = (uint32_t)(b * NN + i);
        if (out[(size_t)idx * 5] == 0.0f) {
            uint32_t u = threefry_bits(idx) >> 9;
            if ((int)(u >> 15) < C) out[(size_t)idx * 5] = -1.0f;
        }
    }
    __syncthreads();
    uint32_t cnt = scnt; if (cnt > CAP) cnt = CAP;
    uint32_t baseRank = sBase;
    for (uint32_t k = t; k < cnt; k += 256) {
        uint32_t u = lu[k], n = li[k];
        if (n / (uint32_t)CHSZ != (uint32_t)ch) continue;
        uint32_t r = baseRank;
        for (uint32_t j = 0; j < cnt; ++j)
            r += (lu[j] > u || (lu[j] == u && li[j] < n)) ? 1u : 0u;
        if (r >= cutoff) out[((size_t)b * NN + n) * 5] = -1.0f;
    }
}

extern "C" void kernel_launch(void* const* d_in, const int* in_sizes, int n_in,
                              void* d_out, int out_size, void* d_ws, size_t ws_size,
                              hipStream_t stream) {
    // d_in[0] = cls_scores (shape-relevant only, never read)
    const float4* gt  = (const float4*)d_in[1];
    const float4* anc = (const float4*)d_in[2];
    float* out = (float*)d_out;
    uint32_t* w = (uint32_t*)d_ws;
    bool big = (ws_size >= WS_NEED_ALL);
    uint32_t* rnk = w + WS_RNK;
    uint32_t* seg = w + WS_SEG;

    if (big) {
        k_main<<<dim3(NBLK, NB), 256, 0, stream>>>(gt, anc, out, w, rnk, seg);
        k_post<<<dim3(NCH, NB), 256, 0, stream>>>(out, w, rnk, seg);
    } else {
        if (ws_size >= ((size_t)WS_SEG) * 4) {
            k_main<<<dim3(NBLK, NB), 256, 0, stream>>>(gt, anc, out, w, rnk, rnk);
        } else {
            k_main<<<dim3(NBLK, NB), 256, 0, stream>>>(gt, anc, out, w, w + WS_PART, w + WS_PART);
        }
        k_post_slow<<<dim3(NCH, NB), 256, 0, stream>>>(out, w);
    }
}

// Round 9
// 103.810 us; speedup vs baseline: 1.7869x; 1.0668x over previous
//
#include <hip/hip_runtime.h>
#include <stdint.h>

// Bit-exact f32 vs numpy reference required for label thresholds:
// kill FMA contraction everywhere.
#pragma clang fp contract(off)

#define NB 16       // batch
#define NA 12       // anchors per cell
#define NH 64
#define NW 64
#define NG 64       // gt boxes per batch
#define NN (NA*NH*NW)   // 49152 anchors per batch row
#define NBLK (NN/256)   // 192 k_main tiles per batch row
#define NCH 64          // k_post chunks per row (64 x 16 = 1024 blocks)
#define CHSZ (NN/NCH)   // 768 anchors per k_post block
#define CAP 2048        // boundary-bin LDS list capacity (expected ~137)
#define SEGC 8          // segment capacity per (row,bin,tile)

// ws layout (uint32 index) — nothing needs pre-zeroing (counts come from the
// tile hists; harness poisons ws with 0xAA every launch):
// [0 .. 3072)     per-tile packed (pos<<16|neg) partials
// [WS_BH ..)      tile hists, TRANSPOSED [b][word d<128][tile], word d packs
//                 fine bins (2d,2d+1) as u16 pair
// [WS_BH4 ..)     coarse-16 summaries, TRANSPOSED [b][word h<8][tile],
//                 word h packs coarse bins (2h,2h+1) as u16 pair
// [WS_RNK ..)     rnk32 = (u23<<2)|lab2 per anchor
// [WS_SEG ..)     segments [b][bin][tile][slot<SEGC]: (u23<<8)|local_n8
#define WS_PART 0
#define WS_BH   4096
#define WS_BH4  (WS_BH + NB*128*NBLK)                  // 397312
#define WS_RNK  (WS_BH4 + NB*8*NBLK)                   // 421888
#define WS_SEG  (WS_RNK + NB*NN)                       // 1208320
#define WS_NEED_ALL (((size_t)WS_SEG + (size_t)NB*256*NBLK*SEGC) * 4)  // ~30 MB

__device__ __forceinline__ uint32_t rotl32(uint32_t x, int r) {
    return (x << r) | (x >> (32 - r));
}

// threefry2x32, key = jax.random.key(42) -> (0, 42), partitionable counters:
// x0 = hi(flat_idx)=0, x1 = lo(flat_idx)=i; 32-bit draw = out0 ^ out1.
// Verified bit-exact (absmax 0 in R1-R8).
__device__ uint32_t threefry_bits(uint32_t idx) {
    const uint32_t ks0 = 0u, ks1 = 42u, ks2 = 0x1BD11BDAu ^ 0u ^ 42u;
    uint32_t x0 = ks0;
    uint32_t x1 = idx + ks1;
#define RND(r) { x0 += x1; x1 = rotl32(x1, r); x1 ^= x0; }
    RND(13) RND(15) RND(26) RND(6)
    x0 += ks1; x1 += ks2 + 1u;
    RND(17) RND(29) RND(16) RND(24)
    x0 += ks2; x1 += ks0 + 2u;
    RND(13) RND(15) RND(26) RND(6)
    x0 += ks0; x1 += ks1 + 3u;
    RND(17) RND(29) RND(16) RND(24)
    x0 += ks1; x1 += ks2 + 4u;
    RND(13) RND(15) RND(26) RND(6)
    x0 += ks2; x1 += ks0 + 5u;
#undef RND
    return x0 ^ x1;
}

// Division-free argmax (verified bit-exact R1-R8) + wave-uniform y-prune (R8
// win): boxes with no y-overlap give ov == 1e-10 for every lane — exactly the
// substituted value, which can never win the running max (ties keep earlier).
__global__ __launch_bounds__(256) void k_main(const float4* __restrict__ gt,
                                              const float4* __restrict__ anc,
                                              float* __restrict__ out,
                                              uint32_t* __restrict__ w,
                                              uint32_t* __restrict__ rnk,
                                              uint32_t* __restrict__ seg) {
#pragma clang fp contract(off)
    const int b = blockIdx.y;
    const int n = blockIdx.x * 256 + threadIdx.x;
    const int t = threadIdx.x;

    __shared__ float4 sgv[NG];    // (gx0, gy0, gx1, gy1)
    __shared__ float  sgar[NG];   // gt area
    __shared__ float4 sg0[NG];    // batch-0 boxes (reference gt_flat indexing bug)
    __shared__ float  sout[256 * 5];
    __shared__ uint32_t sred[4];  // per-wave packed (pos<<16 | neg)
    __shared__ uint32_t shist[256];  // fine (top-8-bit) rank-key hist, label-0
    shist[t] = 0;
    if (t < NG) {
        float4 g = gt[b * NG + t];
        sgv[t] = make_float4(g.x, g.y, g.x + g.z, g.y + g.w);
        sgar[t] = g.z * g.w;
    } else if (t < 2 * NG) {
        sg0[t - NG] = gt[t - NG];
    }
    __syncthreads();

    float4 a = anc[n];
    float ax1 = a.x + a.z;
    float ay1 = a.y + a.w;
    float aar = a.z * a.w;
    bool keep = (a.x >= 0.f) && (a.y >= 0.f) && (a.z >= 0.f) && (a.w >= 0.f)
             && (a.x <= 63.f) && (a.y <= 63.f)
             && ((ax1 - 1.0f) <= 63.f) && ((ay1 - 1.0f) <= 63.f);

    float nb_ = 1e-10f, db_ = 1.0f;   // best fraction (virtual init = 1e-10/1)
    int ib_ = 0;
    if (__ballot(keep) != 0ull) {     // whole-wave skip (~12% of waves)
        // Wave-uniform y-overlap mask: lane L tests box L (a.y, ay1 uniform).
        int lane = t & 63;
        float4 gl = sgv[lane];
        float rih = fminf(ay1, gl.w) - fmaxf(a.y, gl.y);
        uint64_t M = __ballot(rih > 0.0f);

        bool tookwin = false;
        int minEmpty = 64;            // first evaluated candidate with inter==0
        uint64_t m = M;
        while (m) {
            int g = (int)__builtin_ctzll(m); m &= m - 1;
            float4 gv = sgv[g];
            float iw = fmaxf(0.0f, fminf(ax1, gv.z) - fmaxf(a.x, gv.x));
            float ih = fmaxf(0.0f, fminf(ay1, gv.w) - fmaxf(a.y, gv.y));
            float inter = iw * ih;
            if (inter == 0.0f) {      // value == 1e-10 exactly: can never win
                if (g < minEmpty) minEmpty = g;
                continue;
            }
            float uni = (aar + sgar[g]) - inter;
            float p = inter * db_;
            float q = nb_ * uni;
            float d_ = p - q;
            float band = 0x1p-20f * fmaxf(p, q);
            bool win;
            if (__builtin_expect(fabsf(d_) <= band, 0)) {
                float ovg = inter / uni;
                float ovb = nb_ / db_;
                win = ovg > ovb;      // rounded compare; ties keep earlier
            } else {
                win = d_ > band;      // provable rounded ordering outside band
            }
            if (win) { nb_ = inter; db_ = uni; ib_ = g; tookwin = true; }
        }
        if (!tookwin) {
            // best is exactly 1e-10: reference argmax = first g with ov==1e-10
            // = min(first non-candidate, first evaluated-empty).
            uint64_t notM = ~M;
            int firstNon = notM ? (int)__builtin_ctzll(notM) : 64;
            int e = firstNon < minEmpty ? firstNon : minEmpty;
            if (__builtin_expect(e >= 64, 0)) {
                // measure-zero guard: full reference loop.
                {
                    float4 gv = sgv[0];
                    float iw = fmaxf(0.0f, fminf(ax1, gv.z) - fmaxf(a.x, gv.x));
                    float ih = fmaxf(0.0f, fminf(ay1, gv.w) - fmaxf(a.y, gv.y));
                    float inter = iw * ih;
                    float uni = (aar + sgar[0]) - inter;
                    nb_ = inter; db_ = uni; ib_ = 0;
                    if (inter == 0.0f) { nb_ = 1e-10f; db_ = 1.0f; }
                }
                for (int g = 1; g < NG; ++g) {
                    float4 gv = sgv[g];
                    float iw = fmaxf(0.0f, fminf(ax1, gv.z) - fmaxf(a.x, gv.x));
                    float ih = fmaxf(0.0f, fminf(ay1, gv.w) - fmaxf(a.y, gv.y));
                    float inter = iw * ih;
                    float uni = (aar + sgar[g]) - inter;
                    float ng_ = inter, dg_ = uni;
                    if (inter == 0.0f) { ng_ = 1e-10f; dg_ = 1.0f; }
                    float p = ng_ * db_;
                    float q = nb_ * dg_;
                    float d_ = p - q;
                    float band = 0x1p-20f * fmaxf(p, q);
                    bool same = (ng_ == nb_) && (dg_ == db_);
                    bool win;
                    if (!same && fabsf(d_) <= band) {
                        win = (ng_ / dg_) > (nb_ / db_);
                    } else {
                        win = d_ > band;
                    }
                    if (win) { nb_ = ng_; db_ = dg_; ib_ = g; }
                }
            } else {
                ib_ = e;
            }
        }
    }
    float best = nb_ / db_;    // == reference max_ov, bit-exact

    float label = -1.0f;
    if (keep) label = (best >= 0.7f) ? 1.0f : ((best <= 0.3f) ? 0.0f : -1.0f);

    // pos/neg: ballot + LDS combine + one plain store per block (R3 win).
    uint64_t bp = __ballot(keep && (best > 0.7f));   // pos (strict >)
    uint64_t bn = __ballot(keep && (best < 0.3f));   // neg (strict <)
    if ((t & 63) == 0)
        sred[t >> 6] = ((uint32_t)__popcll(bp) << 16) | (uint32_t)__popcll(bn);

    float t0 = 0.f, t1 = 0.f, t2 = 0.f, t3 = 0.f;
    if (keep) {
        float4 g0 = sg0[ib_];                 // always batch-0 (ref bug)
        t0 = a.x - g0.x / 16.0f;
        t1 = a.y - g0.y / 16.0f;
        t2 = a.z - g0.z / 16.0f;
        t3 = a.w - g0.w / 16.0f;
    }

    // Stage to LDS (stride 5, coprime with 32 banks), then coalesced stores.
    sout[t * 5 + 0] = label;
    sout[t * 5 + 1] = t0; sout[t * 5 + 2] = t1;
    sout[t * 5 + 3] = t2; sout[t * 5 + 4] = t3;

    uint32_t idx = (uint32_t)(b * NN + n);
    uint32_t u = threefry_bits(idx) >> 9;     // 23-bit rank key
    if (label == 0.0f) {
        uint32_t bin = u >> 15;
        uint32_t slot = atomicAdd(&shist[bin], 1u);   // free deterministic-set slot
        if (seg && slot < SEGC)
            seg[(((uint32_t)b * 256 + bin) * NBLK + (uint32_t)blockIdx.x) * SEGC + slot]
                = (u << 8) | ((uint32_t)t & 255u);    // (u23 | local_n8)
    }
    if (rnk) {
        uint32_t lab2 = (label == 0.0f) ? 2u : ((label == 1.0f) ? 1u : 0u);
        rnk[idx] = (u << 2) | lab2;
    }

    __syncthreads();
    if (t == 0)
        w[WS_PART + b * NBLK + blockIdx.x] = sred[0] + sred[1] + sred[2] + sred[3];
    // Transposed fine tile-hist store: [b][word t][tile] (R6 win).
    if (t < 128)
        w[WS_BH + (b * 128 + t) * NBLK + blockIdx.x] =
            (shist[2 * t] & 0xFFFFu) | (shist[2 * t + 1] << 16);
    // NEW: coarse-16 summary — word h packs coarse bins (2h, 2h+1); coarse
    // bin c = sum of fine bins [16c, 16c+16). Cuts k_post hist traffic 8x.
    if (t < 8) {
        uint32_t lo = 0, hi = 0;
#pragma unroll
        for (int k = 0; k < 16; ++k) {
            lo += shist[t * 32 + k];
            hi += shist[t * 32 + 16 + k];
        }
        w[WS_BH4 + (b * 8 + t) * NBLK + blockIdx.x] = (lo & 0xFFFFu) | (hi << 16);
    }
    float* ob = out + ((size_t)b * NN + (size_t)blockIdx.x * 256) * 5;
#pragma unroll
    for (int k = 0; k < 5; ++k) ob[k * 256 + t] = sout[k * 256 + t];
}

// Grid = (NCH, NB) = 1024 blocks. Each block redundantly computes row stats
// via the 2-LEVEL hist (12 KB reads/block, was 98 KB — the R8 ~20us wall),
// gathers boundary-bin entries from segments (R7 win), then disables only
// its own CHSZ-anchor chunk.
__global__ __launch_bounds__(256) void k_post(float* __restrict__ out,
                                              const uint32_t* __restrict__ w,
                                              const uint32_t* __restrict__ rnk,
                                              const uint32_t* __restrict__ seg) {
    const int b = blockIdx.y;
    const int ch = blockIdx.x;
    const int t = threadIdx.x;
    __shared__ uint32_t rp[256], rn[256];
    __shared__ uint32_t s4p[64];            // hist partials (packed u16 pairs)
    __shared__ uint32_t hb[16];             // coarse-16 / fine-16 counts
    __shared__ uint32_t lu[CAP], li[CAP];   // boundary-bin entries (row-wide)
    __shared__ uint32_t scnt;
    __shared__ int sC4, sC;
    __shared__ uint32_t sB4, sBase;
    if (t == 0) scnt = 0;

    // 1. pos/neg from the 3072 packed partials (uint4 loads).
    uint32_t sp = 0, sn = 0;
    {
        const uint4* p4 = (const uint4*)(w + WS_PART);
#pragma unroll
        for (int k = 0; k < 3; ++k) {
            uint4 v = p4[t + k * 256];
            sp += (v.x >> 16) + (v.y >> 16) + (v.z >> 16) + (v.w >> 16);
            sn += (v.x & 0xFFFFu) + (v.y & 0xFFFFu) + (v.z & 0xFFFFu) + (v.w & 0xFFFFu);
        }
    }
    rp[t] = sp; rn[t] = sn;
    __syncthreads();
    for (int s = 128; s > 0; s >>= 1) {
        if (t < s) { rp[t] += rp[t + s]; rn[t] += rn[t + s]; }
        __syncthreads();
    }
    uint32_t pos = rp[0], neg = rn[0];
    uint32_t cutoff = 3u * pos; if (cutoff < 1u) cutoff = 1u;
    if (neg <= cutoff) return;     // uniform across grid: no disabling at all

    // 2a. coarse-16 row hist from summaries (6 KB): 8 threads/word, 24 tiles
    // each (contiguous uint4). Packed u16 adds safe (<= 49152 per half).
    if (t < 64) {
        int d = t >> 3, part = t & 7;
        const uint4* q4 = (const uint4*)(w + WS_BH4 + (b * 8 + d) * NBLK + part * 24);
        uint32_t c = 0;
#pragma unroll
        for (int k = 0; k < 6; ++k) { uint4 v = q4[k]; c += v.x + v.y + v.z + v.w; }
        s4p[t] = c;
    }
    __syncthreads();
    if (t < 8) {
        uint32_t c = 0;
#pragma unroll
        for (int k = 0; k < 8; ++k) c += s4p[t * 8 + k];
        hb[2 * t] = c & 0xFFFFu; hb[2 * t + 1] = c >> 16;
    }
    __syncthreads();
    if (t == 0) {
        uint32_t cum = 0; int C4 = -1; uint32_t base4 = 0;
        for (int c = 15; c >= 0; --c) {
            if (cum + hb[c] >= cutoff) { C4 = c; base4 = cum; break; }
            cum += hb[c];
        }
        sC4 = C4; sB4 = base4;
    }
    __syncthreads();
    int C4 = sC4;
    if (C4 < 0) return;            // row has < cutoff label-0 -> keep all

    // 2b. fine scan inside coarse bin C4: fine words [8*C4, 8*C4+8) (6 KB).
    if (t < 64) {
        int d = t >> 3, part = t & 7;
        const uint4* q4 = (const uint4*)(w + WS_BH + (b * 128 + 8 * C4 + d) * NBLK + part * 24);
        uint32_t c = 0;
#pragma unroll
        for (int k = 0; k < 6; ++k) { uint4 v = q4[k]; c += v.x + v.y + v.z + v.w; }
        s4p[t] = c;
    }
    __syncthreads();
    if (t < 8) {
        uint32_t c = 0;
#pragma unroll
        for (int k = 0; k < 8; ++k) c += s4p[t * 8 + k];
        hb[2 * t] = c & 0xFFFFu; hb[2 * t + 1] = c >> 16;
    }
    __syncthreads();
    if (t == 0) {
        uint32_t cum = sB4; int C = -1; uint32_t base = 0;
        for (int j = 15; j >= 0; --j) {
            if (cum + hb[j] >= cutoff) { C = 16 * C4 + j; base = cum; break; }
            cum += hb[j];
        }
        sC = C; sBase = base;      // guaranteed found: coarse bin crossed cutoff
    }
    __syncthreads();
    int C = sC;

    // 4a. gather bin-C entries from segments: thread t<192 handles tile t.
    if (t < NBLK) {
        uint32_t cw = w[WS_BH + (b * 128 + (C >> 1)) * NBLK + t];
        uint32_t cnt_t = (C & 1) ? (cw >> 16) : (cw & 0xFFFFu);
        if (cnt_t <= SEGC) {
            const uint32_t* sg = seg +
                (((uint32_t)b * 256 + (uint32_t)C) * NBLK + (uint32_t)t) * SEGC;
            for (uint32_t k = 0; k < cnt_t; ++k) {
                uint32_t v = sg[k];
                uint32_t p_ = atomicAdd(&scnt, 1u);
                if (p_ < CAP) { lu[p_] = v >> 8; li[p_] = (uint32_t)t * 256u + (v & 255u); }
            }
        } else {
            // overflow (P ~ 1e-8): scan this tile's 256 rnk words directly.
            const uint32_t* rr = rnk + (size_t)b * NN + (size_t)t * 256;
            for (int k = 0; k < 256; ++k) {
                uint32_t val = rr[k];
                if ((val & 3u) == 2u && (int)((val >> 2) >> 15) == C) {
                    uint32_t p_ = atomicAdd(&scnt, 1u);
                    if (p_ < CAP) { lu[p_] = val >> 2; li[p_] = (uint32_t)t * 256u + (uint32_t)k; }
                }
            }
        }
    }

    // 4b. own chunk: fine bin < C -> disabled (768 anchors, uint4 reads).
    {
        const uint4* r4 = (const uint4*)(rnk + (size_t)b * NN + (size_t)ch * CHSZ);
        if (t < CHSZ / 4) {
            uint4 v = r4[t];
            uint32_t vv[4] = {v.x, v.y, v.z, v.w};
#pragma unroll
            for (int k = 0; k < 4; ++k) {
                uint32_t val = vv[k];
                if ((val & 3u) == 2u && (int)((val >> 2) >> 15) < C) {
                    int i = ch * CHSZ + t * 4 + k;
                    out[((size_t)b * NN + i) * 5] = -1.0f;
                }
            }
        }
    }
    __syncthreads();

    // 5. exact rank resolution for boundary entries in MY chunk.
    uint32_t cnt = scnt; if (cnt > CAP) cnt = CAP;
    uint32_t baseRank = sBase;
    for (uint32_t k = t; k < cnt; k += 256) {
        uint32_t u = lu[k], n = li[k];
        if (n / (uint32_t)CHSZ != (uint32_t)ch) continue;
        uint32_t r = baseRank;
        for (uint32_t j = 0; j < cnt; ++j) {
            // descending u, ties by smaller index first (stable argsort)
            r += (lu[j] > u || (lu[j] == u && li[j] < n)) ? 1u : 0u;
        }
        if (r >= cutoff) out[((size_t)b * NN + n) * 5] = -1.0f;
    }
}

// Fallback post kernel if ws is too small for rnk/segments: full scans,
// recomputes threefry from out labels. (Never taken with the observed
// 256 MiB ws; kept for safety.)
__global__ __launch_bounds__(256) void k_post_slow(float* __restrict__ out,
                                                   const uint32_t* __restrict__ w) {
    const int b = blockIdx.y;
    const int ch = blockIdx.x;
    const int t = threadIdx.x;
    __shared__ uint32_t rp[256], rn[256];
    __shared__ uint32_t sph[256];
    __shared__ uint32_t hcnt[256];
    __shared__ uint32_t lu[CAP], li[CAP];
    __shared__ uint32_t scnt;
    __shared__ int sC;
    __shared__ uint32_t sBase;
    if (t == 0) scnt = 0;
    uint32_t sp = 0, sn = 0;
    {
        const uint4* p4 = (const uint4*)(w + WS_PART);
#pragma unroll
        for (int k = 0; k < 3; ++k) {
            uint4 v = p4[t + k * 256];
            sp += (v.x >> 16) + (v.y >> 16) + (v.z >> 16) + (v.w >> 16);
            sn += (v.x & 0xFFFFu) + (v.y & 0xFFFFu) + (v.z & 0xFFFFu) + (v.w & 0xFFFFu);
        }
    }
    rp[t] = sp; rn[t] = sn;
    __syncthreads();
    for (int s = 128; s > 0; s >>= 1) {
        if (t < s) { rp[t] += rp[t + s]; rn[t] += rn[t + s]; }
        __syncthreads();
    }
    uint32_t pos = rp[0], neg = rn[0];
    uint32_t cutoff = 3u * pos; if (cutoff < 1u) cutoff = 1u;
    if (neg <= cutoff) return;
    {
        int d = t >> 1, half = t & 1;
        const uint4* h4 = (const uint4*)(w + WS_BH + (b * 128 + d) * NBLK + half * 96);
        uint32_t c = 0;
#pragma unroll 4
        for (int k = 0; k < 24; ++k) { uint4 v = h4[k]; c += v.x + v.y + v.z + v.w; }
        sph[t] = c;
    }
    __syncthreads();
    if (t < 128) {
        uint32_t v0 = sph[2 * t], v1 = sph[2 * t + 1];
        hcnt[2 * t]     = (v0 & 0xFFFFu) + (v1 & 0xFFFFu);
        hcnt[2 * t + 1] = (v0 >> 16) + (v1 >> 16);
    }
    __syncthreads();
    if (t == 0) {
        uint32_t cum = 0; int C = -1; uint32_t base = 0;
        for (int c = 255; c >= 0; --c) {
            if (cum + hcnt[c] >= cutoff) { C = c; base = cum; break; }
            cum += hcnt[c];
        }
        sC = C; sBase = base;
    }
    __syncthreads();
    int C = sC;
    if (C < 0) return;
    for (int i = t; i < NN; i += 256) {
        uint32_t idx = (uint32_t)(b * NN + i);
        if (out[(size_t)idx * 5] == 0.0f) {
            uint32_t u = threefry_bits(idx) >> 9;
            if ((int)(u >> 15) == C) {
                uint32_t p_ = atomicAdd(&scnt, 1u);
                if (p_ < CAP) { lu[p_] = u; li[p_] = (uint32_t)i; }
            }
        }
    }
    for (int i2 = t; i2 < CHSZ; i2 += 256) {
        int i = ch * CHSZ + i2;
        uint32_t idx = (uint32_t)(b * NN + i);
        if (out[(size_t)idx * 5] == 0.0f) {
            uint32_t u = threefry_bits(idx) >> 9;
            if ((int)(u >> 15) < C) out[(size_t)idx * 5] = -1.0f;
        }
    }
    __syncthreads();
    uint32_t cnt = scnt; if (cnt > CAP) cnt = CAP;
    uint32_t baseRank = sBase;
    for (uint32_t k = t; k < cnt; k += 256) {
        uint32_t u = lu[k], n = li[k];
        if (n / (uint32_t)CHSZ != (uint32_t)ch) continue;
        uint32_t r = baseRank;
        for (uint32_t j = 0; j < cnt; ++j)
            r += (lu[j] > u || (lu[j] == u && li[j] < n)) ? 1u : 0u;
        if (r >= cutoff) out[((size_t)b * NN + n) * 5] = -1.0f;
    }
}

extern "C" void kernel_launch(void* const* d_in, const int* in_sizes, int n_in,
                              void* d_out, int out_size, void* d_ws, size_t ws_size,
                              hipStream_t stream) {
    // d_in[0] = cls_scores (shape-relevant only, never read)
    const float4* gt  = (const float4*)d_in[1];
    const float4* anc = (const float4*)d_in[2];
    float* out = (float*)d_out;
    uint32_t* w = (uint32_t*)d_ws;
    bool big = (ws_size >= WS_NEED_ALL);
    uint32_t* rnk = big ? (w + WS_RNK) : (uint32_t*)nullptr;
    uint32_t* seg = big ? (w + WS_SEG) : (uint32_t*)nullptr;

    k_main<<<dim3(NBLK, NB), 256, 0, stream>>>(gt, anc, out, w, rnk, seg);
    if (big) {
        k_post<<<dim3(NCH, NB), 256, 0, stream>>>(out, w, rnk, seg);
    } else {
        k_post_slow<<<dim3(NCH, NB), 256, 0, stream>>>(out, w);
    }
}

// Round 10
// 98.883 us; speedup vs baseline: 1.8759x; 1.0498x over previous
//
#include <hip/hip_runtime.h>
#include <stdint.h>

// Bit-exact f32 vs numpy reference required for label thresholds:
// kill FMA contraction everywhere.
#pragma clang fp contract(off)

#define NB 16       // batch
#define NA 12       // anchors per cell
#define NH 64
#define NW 64
#define NG 64       // gt boxes per batch
#define NN (NA*NH*NW)   // 49152 anchors per batch row
#define NBLK (NN/256)   // 192 k_main tiles per batch row
#define NCH 64          // k_post chunks per row (64 x 16 = 1024 blocks)
#define CHSZ (NN/NCH)   // 768 anchors per k_post block
#define CAP 2048        // boundary-bin LDS list capacity (expected ~137)
#define SEGC 8          // segment capacity per (row,bin,tile)

// ws layout (uint32 index) — nothing needs pre-zeroing (counts come from the
// tile hists; harness poisons ws with 0xAA every launch):
// [0 .. 3072)     per-tile packed (pos<<16|neg) partials
// [WS_BH ..)      tile hists, TRANSPOSED [b][word d<128][tile], word d packs
//                 fine bins (2d,2d+1) as u16 pair
// [WS_BH4 ..)     coarse-16 summaries, TRANSPOSED [b][word h<8][tile]
// [WS_RNK ..)     rnk32 = (u23<<2)|lab2 per anchor
// [WS_SEG ..)     segments [b][bin][tile][slot<SEGC]: (u23<<8)|local_n8
#define WS_PART 0
#define WS_BH   4096
#define WS_BH4  (WS_BH + NB*128*NBLK)                  // 397312
#define WS_RNK  (WS_BH4 + NB*8*NBLK)                   // 421888
#define WS_SEG  (WS_RNK + NB*NN)                       // 1208320
#define WS_NEED_ALL (((size_t)WS_SEG + (size_t)NB*256*NBLK*SEGC) * 4)  // ~30 MB

__device__ __forceinline__ uint32_t rotl32(uint32_t x, int r) {
    return (x << r) | (x >> (32 - r));
}

__device__ __forceinline__ float readlane_f(float v, int lane) {
    return __builtin_bit_cast(float,
        __builtin_amdgcn_readlane(__builtin_bit_cast(int, v), lane));
}

// threefry2x32, key = jax.random.key(42) -> (0, 42), partitionable counters:
// x0 = hi(flat_idx)=0, x1 = lo(flat_idx)=i; 32-bit draw = out0 ^ out1.
// Verified bit-exact (absmax 0 in R1-R9).
__device__ uint32_t threefry_bits(uint32_t idx) {
    const uint32_t ks0 = 0u, ks1 = 42u, ks2 = 0x1BD11BDAu ^ 0u ^ 42u;
    uint32_t x0 = ks0;
    uint32_t x1 = idx + ks1;
#define RND(r) { x0 += x1; x1 = rotl32(x1, r); x1 ^= x0; }
    RND(13) RND(15) RND(26) RND(6)
    x0 += ks1; x1 += ks2 + 1u;
    RND(17) RND(29) RND(16) RND(24)
    x0 += ks2; x1 += ks0 + 2u;
    RND(13) RND(15) RND(26) RND(6)
    x0 += ks0; x1 += ks1 + 3u;
    RND(17) RND(29) RND(16) RND(24)
    x0 += ks1; x1 += ks2 + 4u;
    RND(13) RND(15) RND(26) RND(6)
    x0 += ks2; x1 += ks0 + 5u;
#undef RND
    return x0 ^ x1;
}

// Division-free argmax (verified bit-exact R1-R9) + wave-uniform y-prune (R8)
// + NEW register-resident box data: lane L holds box L's coords; the
// candidate loop broadcasts via readlane (g is wave-uniform) — no LDS reads
// or ih recompute in the loop. Empty candidates (inter==0) lose automatically:
// p=0 => d=-q<0 <= band fails, |d|<=band fails (band=q*2^-20 < q) => win=false,
// identical to the old `continue`.
__global__ __launch_bounds__(256) void k_main(const float4* __restrict__ gt,
                                              const float4* __restrict__ anc,
                                              float* __restrict__ out,
                                              uint32_t* __restrict__ w,
                                              uint32_t* __restrict__ rnk,
                                              uint32_t* __restrict__ seg) {
#pragma clang fp contract(off)
    const int b = blockIdx.y;
    const int n = blockIdx.x * 256 + threadIdx.x;
    const int t = threadIdx.x;
    const int lane = t & 63;

    __shared__ float4 sg0[NG];    // batch-0 boxes (reference gt_flat indexing bug)
    __shared__ float  sout[256 * 5];
    __shared__ uint32_t sred[4];  // per-wave packed (pos<<16 | neg)
    __shared__ uint32_t shist[256];  // fine (top-8-bit) rank-key hist, label-0
    shist[t] = 0;
    if (t < NG) sg0[t] = gt[t];

    // Per-lane register copy of box `lane` for THIS batch row.
    float4 gL = gt[b * NG + lane];
    float gx0L = gL.x, gy0L = gL.y;
    float gx1L = gL.x + gL.z;            // exact ref op order
    float gy1L = gL.y + gL.w;
    float areaL = gL.z * gL.w;

    float4 a = anc[n];
    float ax1 = a.x + a.z;
    float ay1 = a.y + a.w;
    float aar = a.z * a.w;
    bool keep = (a.x >= 0.f) && (a.y >= 0.f) && (a.z >= 0.f) && (a.w >= 0.f)
             && (a.x <= 63.f) && (a.y <= 63.f)
             && ((ax1 - 1.0f) <= 63.f) && ((ay1 - 1.0f) <= 63.f);

    float nb_ = 1e-10f, db_ = 1.0f;   // best fraction (virtual init = 1e-10/1)
    int ib_ = 0;
    if (__ballot(keep) != 0ull) {     // whole-wave skip (~12% of waves)
        // Wave-uniform y-overlap: a.y/ay1 constant across the wave's 64 j's.
        float rih = fminf(ay1, gy1L) - fmaxf(a.y, gy0L);
        uint64_t M = __ballot(rih > 0.0f);

        bool tookwin = false;
        int minEmpty = 64;            // first evaluated candidate with inter==0
        uint64_t m = M;
        while (m) {
            int g = (int)__builtin_ctzll(m); m &= m - 1;
            float s_ih  = readlane_f(rih, g);    // >0 for candidates: ih = rih
            float s_gx0 = readlane_f(gx0L, g);
            float s_gx1 = readlane_f(gx1L, g);
            float s_ar  = readlane_f(areaL, g);
            float iw = fmaxf(0.0f, fminf(ax1, s_gx1) - fmaxf(a.x, s_gx0));
            float inter = iw * s_ih;
            bool empty = (inter == 0.0f);
            if (empty && g < minEmpty) minEmpty = g;
            float uni = (aar + s_ar) - inter;
            float p = inter * db_;
            float q = nb_ * uni;
            float d_ = p - q;
            float band = 0x1p-20f * fmaxf(p, q);
            bool win;
            if (__builtin_expect(!empty && fabsf(d_) <= band, 0)) {
                float ovg = inter / uni;
                float ovb = nb_ / db_;
                win = ovg > ovb;      // rounded compare; ties keep earlier
            } else {
                win = d_ > band;      // empty => p=0 => false; outside band provable
            }
            if (win) { nb_ = inter; db_ = uni; ib_ = g; tookwin = true; }
        }
        if (!tookwin) {
            // best is exactly 1e-10: reference argmax = first g with ov==1e-10
            // = min(first non-candidate, first evaluated-empty).
            uint64_t notM = ~M;
            int firstNon = notM ? (int)__builtin_ctzll(notM) : 64;
            int e = firstNon < minEmpty ? firstNon : minEmpty;
            if (__builtin_expect(e >= 64, 0)) {
                // measure-zero guard: full reference loop via readlane.
                for (int g = 0; g < NG; ++g) {
                    float s_gx0 = readlane_f(gx0L, g);
                    float s_gy0 = readlane_f(gy0L, g);
                    float s_gx1 = readlane_f(gx1L, g);
                    float s_gy1 = readlane_f(gy1L, g);
                    float s_ar  = readlane_f(areaL, g);
                    float iw = fmaxf(0.0f, fminf(ax1, s_gx1) - fmaxf(a.x, s_gx0));
                    float ih = fmaxf(0.0f, fminf(ay1, s_gy1) - fmaxf(a.y, s_gy0));
                    float inter = iw * ih;
                    float uni = (aar + s_ar) - inter;
                    float ng_ = inter, dg_ = uni;
                    if (inter == 0.0f) { ng_ = 1e-10f; dg_ = 1.0f; }
                    if (g == 0) { nb_ = ng_; db_ = dg_; ib_ = 0; continue; }
                    float p = ng_ * db_;
                    float q = nb_ * dg_;
                    float d_ = p - q;
                    float band = 0x1p-20f * fmaxf(p, q);
                    bool same = (ng_ == nb_) && (dg_ == db_);
                    bool win;
                    if (!same && fabsf(d_) <= band) {
                        win = (ng_ / dg_) > (nb_ / db_);
                    } else {
                        win = d_ > band;
                    }
                    if (win) { nb_ = ng_; db_ = dg_; ib_ = g; }
                }
            } else {
                ib_ = e;
            }
        }
    }
    float best = nb_ / db_;    // == reference max_ov, bit-exact

    float label = -1.0f;
    if (keep) label = (best >= 0.7f) ? 1.0f : ((best <= 0.3f) ? 0.0f : -1.0f);

    // pos/neg: ballot + LDS combine + one plain store per block (R3 win).
    uint64_t bp = __ballot(keep && (best > 0.7f));   // pos (strict >)
    uint64_t bn = __ballot(keep && (best < 0.3f));   // neg (strict <)
    if ((t & 63) == 0)
        sred[t >> 6] = ((uint32_t)__popcll(bp) << 16) | (uint32_t)__popcll(bn);

    // Barrier here covers: sg0 staging, shist zeroing (IoU loop used no LDS).
    __syncthreads();

    float t0 = 0.f, t1 = 0.f, t2 = 0.f, t3 = 0.f;
    if (keep) {
        float4 g0 = sg0[ib_];                 // always batch-0 (ref bug)
        t0 = a.x - g0.x / 16.0f;
        t1 = a.y - g0.y / 16.0f;
        t2 = a.z - g0.z / 16.0f;
        t3 = a.w - g0.w / 16.0f;
    }

    // Stage to LDS (stride 5, coprime with 32 banks), then coalesced stores.
    sout[t * 5 + 0] = label;
    sout[t * 5 + 1] = t0; sout[t * 5 + 2] = t1;
    sout[t * 5 + 3] = t2; sout[t * 5 + 4] = t3;

    uint32_t idx = (uint32_t)(b * NN + n);
    uint32_t u = threefry_bits(idx) >> 9;     // 23-bit rank key
    if (label == 0.0f) {
        uint32_t bin = u >> 15;
        uint32_t slot = atomicAdd(&shist[bin], 1u);   // free deterministic-set slot
        if (seg && slot < SEGC)
            seg[(((uint32_t)b * 256 + bin) * NBLK + (uint32_t)blockIdx.x) * SEGC + slot]
                = (u << 8) | ((uint32_t)t & 255u);    // (u23 | local_n8)
    }
    if (rnk) {
        uint32_t lab2 = (label == 0.0f) ? 2u : ((label == 1.0f) ? 1u : 0u);
        rnk[idx] = (u << 2) | lab2;
    }

    __syncthreads();
    if (t == 0)
        w[WS_PART + b * NBLK + blockIdx.x] = sred[0] + sred[1] + sred[2] + sred[3];
    // Transposed fine tile-hist store: [b][word t][tile] (R6 win).
    if (t < 128)
        w[WS_BH + (b * 128 + t) * NBLK + blockIdx.x] =
            (shist[2 * t] & 0xFFFFu) | (shist[2 * t + 1] << 16);
    // Coarse-16 summary (R9 win): word h packs coarse bins (2h, 2h+1).
    if (t < 8) {
        uint32_t lo = 0, hi = 0;
#pragma unroll
        for (int k = 0; k < 16; ++k) {
            lo += shist[t * 32 + k];
            hi += shist[t * 32 + 16 + k];
        }
        w[WS_BH4 + (b * 8 + t) * NBLK + blockIdx.x] = (lo & 0xFFFFu) | (hi << 16);
    }
    float* ob = out + ((size_t)b * NN + (size_t)blockIdx.x * 256) * 5;
#pragma unroll
    for (int k = 0; k < 5; ++k) ob[k * 256 + t] = sout[k * 256 + t];
}

// Grid = (NCH, NB) = 1024 blocks. Each block redundantly computes row stats
// via the 2-level hist (R9 win), gathers boundary-bin entries from segments
// (R7 win), then disables only its own CHSZ-anchor chunk.
__global__ __launch_bounds__(256) void k_post(float* __restrict__ out,
                                              const uint32_t* __restrict__ w,
                                              const uint32_t* __restrict__ rnk,
                                              const uint32_t* __restrict__ seg) {
    const int b = blockIdx.y;
    const int ch = blockIdx.x;
    const int t = threadIdx.x;
    __shared__ uint32_t rp[256], rn[256];
    __shared__ uint32_t s4p[64];            // hist partials (packed u16 pairs)
    __shared__ uint32_t hb[16];             // coarse-16 / fine-16 counts
    __shared__ uint32_t lu[CAP], li[CAP];   // boundary-bin entries (row-wide)
    __shared__ uint32_t scnt;
    __shared__ int sC4, sC;
    __shared__ uint32_t sB4, sBase;
    if (t == 0) scnt = 0;

    // 1. pos/neg from the 3072 packed partials (uint4 loads).
    uint32_t sp = 0, sn = 0;
    {
        const uint4* p4 = (const uint4*)(w + WS_PART);
#pragma unroll
        for (int k = 0; k < 3; ++k) {
            uint4 v = p4[t + k * 256];
            sp += (v.x >> 16) + (v.y >> 16) + (v.z >> 16) + (v.w >> 16);
            sn += (v.x & 0xFFFFu) + (v.y & 0xFFFFu) + (v.z & 0xFFFFu) + (v.w & 0xFFFFu);
        }
    }
    rp[t] = sp; rn[t] = sn;
    __syncthreads();
    for (int s = 128; s > 0; s >>= 1) {
        if (t < s) { rp[t] += rp[t + s]; rn[t] += rn[t + s]; }
        __syncthreads();
    }
    uint32_t pos = rp[0], neg = rn[0];
    uint32_t cutoff = 3u * pos; if (cutoff < 1u) cutoff = 1u;
    if (neg <= cutoff) return;     // uniform across grid: no disabling at all

    // 2a. coarse-16 row hist from summaries (6 KB).
    if (t < 64) {
        int d = t >> 3, part = t & 7;
        const uint4* q4 = (const uint4*)(w + WS_BH4 + (b * 8 + d) * NBLK + part * 24);
        uint32_t c = 0;
#pragma unroll
        for (int k = 0; k < 6; ++k) { uint4 v = q4[k]; c += v.x + v.y + v.z + v.w; }
        s4p[t] = c;
    }
    __syncthreads();
    if (t < 8) {
        uint32_t c = 0;
#pragma unroll
        for (int k = 0; k < 8; ++k) c += s4p[t * 8 + k];
        hb[2 * t] = c & 0xFFFFu; hb[2 * t + 1] = c >> 16;
    }
    __syncthreads();
    if (t == 0) {
        uint32_t cum = 0; int C4 = -1; uint32_t base4 = 0;
        for (int c = 15; c >= 0; --c) {
            if (cum + hb[c] >= cutoff) { C4 = c; base4 = cum; break; }
            cum += hb[c];
        }
        sC4 = C4; sB4 = base4;
    }
    __syncthreads();
    int C4 = sC4;
    if (C4 < 0) return;            // row has < cutoff label-0 -> keep all

    // 2b. fine scan inside coarse bin C4 (6 KB).
    if (t < 64) {
        int d = t >> 3, part = t & 7;
        const uint4* q4 = (const uint4*)(w + WS_BH + (b * 128 + 8 * C4 + d) * NBLK + part * 24);
        uint32_t c = 0;
#pragma unroll
        for (int k = 0; k < 6; ++k) { uint4 v = q4[k]; c += v.x + v.y + v.z + v.w; }
        s4p[t] = c;
    }
    __syncthreads();
    if (t < 8) {
        uint32_t c = 0;
#pragma unroll
        for (int k = 0; k < 8; ++k) c += s4p[t * 8 + k];
        hb[2 * t] = c & 0xFFFFu; hb[2 * t + 1] = c >> 16;
    }
    __syncthreads();
    if (t == 0) {
        uint32_t cum = sB4; int C = -1; uint32_t base = 0;
        for (int j = 15; j >= 0; --j) {
            if (cum + hb[j] >= cutoff) { C = 16 * C4 + j; base = cum; break; }
            cum += hb[j];
        }
        sC = C; sBase = base;      // guaranteed found: coarse bin crossed cutoff
    }
    __syncthreads();
    int C = sC;

    // 4a. gather bin-C entries from segments: thread t<192 handles tile t.
    if (t < NBLK) {
        uint32_t cw = w[WS_BH + (b * 128 + (C >> 1)) * NBLK + t];
        uint32_t cnt_t = (C & 1) ? (cw >> 16) : (cw & 0xFFFFu);
        if (cnt_t <= SEGC) {
            const uint32_t* sg = seg +
                (((uint32_t)b * 256 + (uint32_t)C) * NBLK + (uint32_t)t) * SEGC;
            for (uint32_t k = 0; k < cnt_t; ++k) {
                uint32_t v = sg[k];
                uint32_t p_ = atomicAdd(&scnt, 1u);
                if (p_ < CAP) { lu[p_] = v >> 8; li[p_] = (uint32_t)t * 256u + (v & 255u); }
            }
        } else {
            // overflow (P ~ 1e-8): scan this tile's 256 rnk words directly.
            const uint32_t* rr = rnk + (size_t)b * NN + (size_t)t * 256;
            for (int k = 0; k < 256; ++k) {
                uint32_t val = rr[k];
                if ((val & 3u) == 2u && (int)((val >> 2) >> 15) == C) {
                    uint32_t p_ = atomicAdd(&scnt, 1u);
                    if (p_ < CAP) { lu[p_] = val >> 2; li[p_] = (uint32_t)t * 256u + (uint32_t)k; }
                }
            }
        }
    }

    // 4b. own chunk: fine bin < C -> disabled (768 anchors, uint4 reads).
    {
        const uint4* r4 = (const uint4*)(rnk + (size_t)b * NN + (size_t)ch * CHSZ);
        if (t < CHSZ / 4) {
            uint4 v = r4[t];
            uint32_t vv[4] = {v.x, v.y, v.z, v.w};
#pragma unroll
            for (int k = 0; k < 4; ++k) {
                uint32_t val = vv[k];
                if ((val & 3u) == 2u && (int)((val >> 2) >> 15) < C) {
                    int i = ch * CHSZ + t * 4 + k;
                    out[((size_t)b * NN + i) * 5] = -1.0f;
                }
            }
        }
    }
    __syncthreads();

    // 5. exact rank resolution for boundary entries in MY chunk.
    uint32_t cnt = scnt; if (cnt > CAP) cnt = CAP;
    uint32_t baseRank = sBase;
    for (uint32_t k = t; k < cnt; k += 256) {
        uint32_t u = lu[k], n = li[k];
        if (n / (uint32_t)CHSZ != (uint32_t)ch) continue;
        uint32_t r = baseRank;
        for (uint32_t j = 0; j < cnt; ++j) {
            // descending u, ties by smaller index first (stable argsort)
            r += (lu[j] > u || (lu[j] == u && li[j] < n)) ? 1u : 0u;
        }
        if (r >= cutoff) out[((size_t)b * NN + n) * 5] = -1.0f;
    }
}

// Fallback post kernel if ws is too small for rnk/segments (never taken with
// the observed 256 MiB ws; kept for safety).
__global__ __launch_bounds__(256) void k_post_slow(float* __restrict__ out,
                                                   const uint32_t* __restrict__ w) {
    const int b = blockIdx.y;
    const int ch = blockIdx.x;
    const int t = threadIdx.x;
    __shared__ uint32_t rp[256], rn[256];
    __shared__ uint32_t sph[256];
    __shared__ uint32_t hcnt[256];
    __shared__ uint32_t lu[CAP], li[CAP];
    __shared__ uint32_t scnt;
    __shared__ int sC;
    __shared__ uint32_t sBase;
    if (t == 0) scnt = 0;
    uint32_t sp = 0, sn = 0;
    {
        const uint4* p4 = (const uint4*)(w + WS_PART);
#pragma unroll
        for (int k = 0; k < 3; ++k) {
            uint4 v = p4[t + k * 256];
            sp += (v.x >> 16) + (v.y >> 16) + (v.z >> 16) + (v.w >> 16);
            sn += (v.x & 0xFFFFu) + (v.y & 0xFFFFu) + (v.z & 0xFFFFu) + (v.w & 0xFFFFu);
        }
    }
    rp[t] = sp; rn[t] = sn;
    __syncthreads();
    for (int s = 128; s > 0; s >>= 1) {
        if (t < s) { rp[t] += rp[t + s]; rn[t] += rn[t + s]; }
        __syncthreads();
    }
    uint32_t pos = rp[0], neg = rn[0];
    uint32_t cutoff = 3u * pos; if (cutoff < 1u) cutoff = 1u;
    if (neg <= cutoff) return;
    {
        int d = t >> 1, half = t & 1;
        const uint4* h4 = (const uint4*)(w + WS_BH + (b * 128 + d) * NBLK + half * 96);
        uint32_t c = 0;
#pragma unroll 4
        for (int k = 0; k < 24; ++k) { uint4 v = h4[k]; c += v.x + v.y + v.z + v.w; }
        sph[t] = c;
    }
    __syncthreads();
    if (t < 128) {
        uint32_t v0 = sph[2 * t], v1 = sph[2 * t + 1];
        hcnt[2 * t]     = (v0 & 0xFFFFu) + (v1 & 0xFFFFu);
        hcnt[2 * t + 1] = (v0 >> 16) + (v1 >> 16);
    }
    __syncthreads();
    if (t == 0) {
        uint32_t cum = 0; int C = -1; uint32_t base = 0;
        for (int c = 255; c >= 0; --c) {
            if (cum + hcnt[c] >= cutoff) { C = c; base = cum; break; }
            cum += hcnt[c];
        }
        sC = C; sBase = base;
    }
    __syncthreads();
    int C = sC;
    if (C < 0) return;
    for (int i = t; i < NN; i += 256) {
        uint32_t idx = (uint32_t)(b * NN + i);
        if (out[(size_t)idx * 5] == 0.0f) {
            uint32_t u = threefry_bits(idx) >> 9;
            if ((int)(u >> 15) == C) {
                uint32_t p_ = atomicAdd(&scnt, 1u);
                if (p_ < CAP) { lu[p_] = u; li[p_] = (uint32_t)i; }
            }
        }
    }
    for (int i2 = t; i2 < CHSZ; i2 += 256) {
        int i = ch * CHSZ + i2;
        uint32_t idx = (uint32_t)(b * NN + i);
        if (out[(size_t)idx * 5] == 0.0f) {
            uint32_t u = threefry_bits(idx) >> 9;
            if ((int)(u >> 15) < C) out[(size_t)idx * 5] = -1.0f;
        }
    }
    __syncthreads();
    uint32_t cnt = scnt; if (cnt > CAP) cnt = CAP;
    uint32_t baseRank = sBase;
    for (uint32_t k = t; k < cnt; k += 256) {
        uint32_t u = lu[k], n = li[k];
        if (n / (uint32_t)CHSZ != (uint32_t)ch) continue;
        uint32_t r = baseRank;
        for (uint32_t j = 0; j < cnt; ++j)
            r += (lu[j] > u || (lu[j] == u && li[j] < n)) ? 1u : 0u;
        if (r >= cutoff) out[((size_t)b * NN + n) * 5] = -1.0f;
    }
}

extern "C" void kernel_launch(void* const* d_in, const int* in_sizes, int n_in,
                              void* d_out, int out_size, void* d_ws, size_t ws_size,
                              hipStream_t stream) {
    // d_in[0] = cls_scores (shape-relevant only, never read)
    const float4* gt  = (const float4*)d_in[1];
    const float4* anc = (const float4*)d_in[2];
    float* out = (float*)d_out;
    uint32_t* w = (uint32_t*)d_ws;
    bool big = (ws_size >= WS_NEED_ALL);
    uint32_t* rnk = big ? (w + WS_RNK) : (uint32_t*)nullptr;
    uint32_t* seg = big ? (w + WS_SEG) : (uint32_t*)nullptr;

    k_main<<<dim3(NBLK, NB), 256, 0, stream>>>(gt, anc, out, w, rnk, seg);
    if (big) {
        k_post<<<dim3(NCH, NB), 256, 0, stream>>>(out, w, rnk, seg);
    } else {
        k_post_slow<<<dim3(NCH, NB), 256, 0, stream>>>(out, w);
    }
}

// Round 11
// 92.553 us; speedup vs baseline: 2.0042x; 1.0684x over previous
//
#include <hip/hip_runtime.h>
#include <stdint.h>

// Bit-exact f32 vs numpy reference required for label thresholds:
// kill FMA contraction everywhere.
#pragma clang fp contract(off)

#define NB 16       // batch
#define NA 12       // anchors per cell
#define NH 64
#define NW 64
#define NG 64       // gt boxes per batch
#define NN (NA*NH*NW)   // 49152 anchors per batch row
#define NBLK (NN/256)   // 192 k_main tiles per batch row
#define NCH 64          // k_post chunks per row (64 x 16 = 1024 blocks)
#define CHSZ (NN/NCH)   // 768 anchors per k_post block
#define CAP 2048        // boundary-bin LDS list capacity (expected ~137)
#define SEGC 8          // segment capacity per (row,bin,tile)

// ws layout (uint32 index) — nothing needs pre-zeroing (counts come from the
// tile hists; harness poisons ws with 0xAA every launch):
// [0 .. 3072)     per-tile packed (pos<<16|neg) partials
// [WS_BH ..)      tile hists, TRANSPOSED [b][word d<128][tile], word d packs
//                 fine bins (2d,2d+1) as u16 pair
// [WS_BH4 ..)     coarse-16 summaries, TRANSPOSED [b][word h<8][tile]
// [WS_RNK ..)     rnk32 = (u23<<2)|lab2 per anchor
// [WS_SEG ..)     segments [b][bin][tile][slot<SEGC]: (u23<<8)|local_n8
#define WS_PART 0
#define WS_BH   4096
#define WS_BH4  (WS_BH + NB*128*NBLK)                  // 397312
#define WS_RNK  (WS_BH4 + NB*8*NBLK)                   // 421888
#define WS_SEG  (WS_RNK + NB*NN)                       // 1208320
#define WS_NEED_ALL (((size_t)WS_SEG + (size_t)NB*256*NBLK*SEGC) * 4)  // ~30 MB

__device__ __forceinline__ uint32_t rotl32(uint32_t x, int r) {
    return (x << r) | (x >> (32 - r));
}

__device__ __forceinline__ float readlane_f(float v, int lane) {
    return __builtin_bit_cast(float,
        __builtin_amdgcn_readlane(__builtin_bit_cast(int, v), lane));
}

// threefry2x32, key = jax.random.key(42) -> (0, 42), partitionable counters:
// x0 = hi(flat_idx)=0, x1 = lo(flat_idx)=i; 32-bit draw = out0 ^ out1.
// Verified bit-exact (absmax 0 in R1-R10).
__device__ uint32_t threefry_bits(uint32_t idx) {
    const uint32_t ks0 = 0u, ks1 = 42u, ks2 = 0x1BD11BDAu ^ 0u ^ 42u;
    uint32_t x0 = ks0;
    uint32_t x1 = idx + ks1;
#define RND(r) { x0 += x1; x1 = rotl32(x1, r); x1 ^= x0; }
    RND(13) RND(15) RND(26) RND(6)
    x0 += ks1; x1 += ks2 + 1u;
    RND(17) RND(29) RND(16) RND(24)
    x0 += ks2; x1 += ks0 + 2u;
    RND(13) RND(15) RND(26) RND(6)
    x0 += ks0; x1 += ks1 + 3u;
    RND(17) RND(29) RND(16) RND(24)
    x0 += ks1; x1 += ks2 + 4u;
    RND(13) RND(15) RND(26) RND(6)
    x0 += ks2; x1 += ks0 + 5u;
#undef RND
    return x0 ^ x1;
}

// Division-free argmax (verified bit-exact R1-R10) + wave-uniform y-prune (R8)
// + NEW wave-local LDS candidate compaction: candidates' (gx0,gx1,area,rih)
// are compacted once per wave into LDS; hot loop = 1 uniform ds_read_b128 +
// ~20 VALU, branchless. Empty candidates (inter==0) provably lose through the
// normal compare: p=0 => d=-q<0, band=2^-20*q < q => win=false AND no in-band
// flag (|d|=q>band). In-band compares set a sticky flag -> rare whole-lane
// full-reference redo (replaces the per-iteration divergent div branch).
__global__ __launch_bounds__(256) void k_main(const float4* __restrict__ gt,
                                              const float4* __restrict__ anc,
                                              float* __restrict__ out,
                                              uint32_t* __restrict__ w,
                                              uint32_t* __restrict__ rnk,
                                              uint32_t* __restrict__ seg) {
#pragma clang fp contract(off)
    const int b = blockIdx.y;
    const int n = blockIdx.x * 256 + threadIdx.x;
    const int t = threadIdx.x;
    const int lane = t & 63;
    const int wv = t >> 6;

    __shared__ float4 sg0[NG];    // batch-0 boxes (reference gt_flat indexing bug)
    __shared__ float  sout[256 * 5];
    __shared__ uint32_t sred[4];  // per-wave packed (pos<<16 | neg)
    __shared__ uint32_t shist[256];  // fine (top-8-bit) rank-key hist, label-0
    __shared__ float4 sCand[4][64];  // per-wave compacted candidates
    shist[t] = 0;
    if (t < NG) sg0[t] = gt[t];

    // Per-lane register copy of box `lane` for THIS batch row.
    float4 gL = gt[b * NG + lane];
    float gx0L = gL.x, gy0L = gL.y;
    float gx1L = gL.x + gL.z;            // exact ref op order
    float gy1L = gL.y + gL.w;
    float areaL = gL.z * gL.w;

    float4 a = anc[n];
    float ax1 = a.x + a.z;
    float ay1 = a.y + a.w;
    float aar = a.z * a.w;
    bool keep = (a.x >= 0.f) && (a.y >= 0.f) && (a.z >= 0.f) && (a.w >= 0.f)
             && (a.x <= 63.f) && (a.y <= 63.f)
             && ((ax1 - 1.0f) <= 63.f) && ((ay1 - 1.0f) <= 63.f);

    float nb_ = 1e-10f, db_ = 1.0f;   // best fraction (virtual init = 1e-10/1)
    int ib_ = 0;
    if (__ballot(keep) != 0ull) {     // whole-wave skip (~12% of waves)
        // Wave-uniform y-overlap: a.y/ay1 constant across the wave's 64 j's.
        float rih = fminf(ay1, gy1L) - fmaxf(a.y, gy0L);
        uint64_t M = __ballot(rih > 0.0f);

        // Compact candidates into this wave's LDS strip (ascending g order).
        uint64_t lt = (lane == 0) ? 0ull : (~0ull >> (64 - lane));
        if ((M >> lane) & 1ull) {
            int slot = (int)__popcll(M & lt);
            sCand[wv][slot] = make_float4(gx0L, gx1L, areaL, rih);
        }
        int cnt = (int)__popcll(M);

        int minEmpty = 64;            // first evaluated candidate with inter==0
        bool anyband = false;         // sticky: any compare landed in the band
        uint64_t m = M;
        for (int k = 0; k < cnt; ++k) {
            int g = (int)__builtin_ctzll(m); m &= m - 1;
            float4 c = sCand[wv][k];  // broadcast read (uniform address)
            float iw = fmaxf(0.0f, fminf(ax1, c.y) - fmaxf(a.x, c.x));
            float inter = iw * c.w;   // ih == rih exactly (rih > 0 clamps away)
            float uni = (aar + c.z) - inter;
            bool empty = (inter == 0.0f);
            minEmpty = (empty && minEmpty == 64) ? g : minEmpty;
            float p = inter * db_;
            float q = nb_ * uni;
            float d_ = p - q;
            float band = 0x1p-20f * fmaxf(p, q);
            anyband |= (fabsf(d_) <= band);
            bool win = d_ > band;     // empty => p=0 => false; outside band provable
            nb_ = win ? inter : nb_;
            db_ = win ? uni : db_;
            ib_ = win ? g : ib_;
        }

        if (__builtin_expect(anyband, 0)) {
            // Rare exact redo: full reference loop via readlane (handles
            // in-band ordering, ties, same-fraction — verified R8-R10 path).
            nb_ = 1e-10f; db_ = 1.0f; ib_ = 0;
            for (int g = 0; g < NG; ++g) {
                float s_gx0 = readlane_f(gx0L, g);
                float s_gy0 = readlane_f(gy0L, g);
                float s_gx1 = readlane_f(gx1L, g);
                float s_gy1 = readlane_f(gy1L, g);
                float s_ar  = readlane_f(areaL, g);
                float iw = fmaxf(0.0f, fminf(ax1, s_gx1) - fmaxf(a.x, s_gx0));
                float ih = fmaxf(0.0f, fminf(ay1, s_gy1) - fmaxf(a.y, s_gy0));
                float inter = iw * ih;
                float uni = (aar + s_ar) - inter;
                float ng_ = inter, dg_ = uni;
                if (inter == 0.0f) { ng_ = 1e-10f; dg_ = 1.0f; }
                if (g == 0) { nb_ = ng_; db_ = dg_; ib_ = 0; continue; }
                float p = ng_ * db_;
                float q = nb_ * dg_;
                float d_ = p - q;
                float band = 0x1p-20f * fmaxf(p, q);
                bool same = (ng_ == nb_) && (dg_ == db_);
                bool win;
                if (!same && fabsf(d_) <= band) {
                    win = (ng_ / dg_) > (nb_ / db_);
                } else {
                    win = d_ > band;
                }
                if (win) { nb_ = ng_; db_ = dg_; ib_ = g; }
            }
        } else if (nb_ == 1e-10f && db_ == 1.0f) {
            // No candidate won: best is exactly 1e-10; reference argmax =
            // first g with ov==1e-10 = min(first non-candidate, first empty).
            uint64_t notM = ~M;
            int firstNon = notM ? (int)__builtin_ctzll(notM) : 64;
            int e = firstNon < minEmpty ? firstNon : minEmpty;
            if (__builtin_expect(e >= 64, 0)) {
                // measure-zero guard: full reference loop via readlane.
                for (int g = 0; g < NG; ++g) {
                    float s_gx0 = readlane_f(gx0L, g);
                    float s_gy0 = readlane_f(gy0L, g);
                    float s_gx1 = readlane_f(gx1L, g);
                    float s_gy1 = readlane_f(gy1L, g);
                    float s_ar  = readlane_f(areaL, g);
                    float iw = fmaxf(0.0f, fminf(ax1, s_gx1) - fmaxf(a.x, s_gx0));
                    float ih = fmaxf(0.0f, fminf(ay1, s_gy1) - fmaxf(a.y, s_gy0));
                    float inter = iw * ih;
                    float uni = (aar + s_ar) - inter;
                    float ng_ = inter, dg_ = uni;
                    if (inter == 0.0f) { ng_ = 1e-10f; dg_ = 1.0f; }
                    if (g == 0) { nb_ = ng_; db_ = dg_; ib_ = 0; continue; }
                    float p = ng_ * db_;
                    float q = nb_ * dg_;
                    float d_ = p - q;
                    float band = 0x1p-20f * fmaxf(p, q);
                    bool same = (ng_ == nb_) && (dg_ == db_);
                    bool win;
                    if (!same && fabsf(d_) <= band) {
                        win = (ng_ / dg_) > (nb_ / db_);
                    } else {
                        win = d_ > band;
                    }
                    if (win) { nb_ = ng_; db_ = dg_; ib_ = g; }
                }
            } else {
                ib_ = e;
            }
        }
    }
    float best = nb_ / db_;    // == reference max_ov, bit-exact

    float label = -1.0f;
    if (keep) label = (best >= 0.7f) ? 1.0f : ((best <= 0.3f) ? 0.0f : -1.0f);

    // pos/neg: ballot + LDS combine + one plain store per block (R3 win).
    uint64_t bp = __ballot(keep && (best > 0.7f));   // pos (strict >)
    uint64_t bn = __ballot(keep && (best < 0.3f));   // neg (strict <)
    if ((t & 63) == 0)
        sred[t >> 6] = ((uint32_t)__popcll(bp) << 16) | (uint32_t)__popcll(bn);

    // Barrier covers: sg0 staging, shist zeroing (sCand is wave-private).
    __syncthreads();

    float t0 = 0.f, t1 = 0.f, t2 = 0.f, t3 = 0.f;
    if (keep) {
        float4 g0 = sg0[ib_];                 // always batch-0 (ref bug)
        t0 = a.x - g0.x / 16.0f;
        t1 = a.y - g0.y / 16.0f;
        t2 = a.z - g0.z / 16.0f;
        t3 = a.w - g0.w / 16.0f;
    }

    // Stage to LDS (stride 5, coprime with 32 banks), then coalesced stores.
    sout[t * 5 + 0] = label;
    sout[t * 5 + 1] = t0; sout[t * 5 + 2] = t1;
    sout[t * 5 + 3] = t2; sout[t * 5 + 4] = t3;

    uint32_t idx = (uint32_t)(b * NN + n);
    uint32_t u = threefry_bits(idx) >> 9;     // 23-bit rank key
    if (label == 0.0f) {
        uint32_t bin = u >> 15;
        uint32_t slot = atomicAdd(&shist[bin], 1u);   // free deterministic-set slot
        if (seg && slot < SEGC)
            seg[(((uint32_t)b * 256 + bin) * NBLK + (uint32_t)blockIdx.x) * SEGC + slot]
                = (u << 8) | ((uint32_t)t & 255u);    // (u23 | local_n8)
    }
    if (rnk) {
        uint32_t lab2 = (label == 0.0f) ? 2u : ((label == 1.0f) ? 1u : 0u);
        rnk[idx] = (u << 2) | lab2;
    }

    __syncthreads();
    if (t == 0)
        w[WS_PART + b * NBLK + blockIdx.x] = sred[0] + sred[1] + sred[2] + sred[3];
    // Transposed fine tile-hist store: [b][word t][tile] (R6 win).
    if (t < 128)
        w[WS_BH + (b * 128 + t) * NBLK + blockIdx.x] =
            (shist[2 * t] & 0xFFFFu) | (shist[2 * t + 1] << 16);
    // Coarse-16 summary (R9 win): word h packs coarse bins (2h, 2h+1).
    if (t < 8) {
        uint32_t lo = 0, hi = 0;
#pragma unroll
        for (int k = 0; k < 16; ++k) {
            lo += shist[t * 32 + k];
            hi += shist[t * 32 + 16 + k];
        }
        w[WS_BH4 + (b * 8 + t) * NBLK + blockIdx.x] = (lo & 0xFFFFu) | (hi << 16);
    }
    float* ob = out + ((size_t)b * NN + (size_t)blockIdx.x * 256) * 5;
#pragma unroll
    for (int k = 0; k < 5; ++k) ob[k * 256 + t] = sout[k * 256 + t];
}

// Grid = (NCH, NB) = 1024 blocks. Each block redundantly computes row stats
// via the 2-level hist (R9 win), gathers boundary-bin entries from segments
// (R7 win), then disables only its own CHSZ-anchor chunk.
__global__ __launch_bounds__(256) void k_post(float* __restrict__ out,
                                              const uint32_t* __restrict__ w,
                                              const uint32_t* __restrict__ rnk,
                                              const uint32_t* __restrict__ seg) {
    const int b = blockIdx.y;
    const int ch = blockIdx.x;
    const int t = threadIdx.x;
    __shared__ uint32_t rp[256], rn[256];
    __shared__ uint32_t s4p[64];            // hist partials (packed u16 pairs)
    __shared__ uint32_t hb[16];             // coarse-16 / fine-16 counts
    __shared__ uint32_t lu[CAP], li[CAP];   // boundary-bin entries (row-wide)
    __shared__ uint32_t scnt;
    __shared__ int sC4, sC;
    __shared__ uint32_t sB4, sBase;
    if (t == 0) scnt = 0;

    // 1. pos/neg from the 3072 packed partials (uint4 loads).
    uint32_t sp = 0, sn = 0;
    {
        const uint4* p4 = (const uint4*)(w + WS_PART);
#pragma unroll
        for (int k = 0; k < 3; ++k) {
            uint4 v = p4[t + k * 256];
            sp += (v.x >> 16) + (v.y >> 16) + (v.z >> 16) + (v.w >> 16);
            sn += (v.x & 0xFFFFu) + (v.y & 0xFFFFu) + (v.z & 0xFFFFu) + (v.w & 0xFFFFu);
        }
    }
    rp[t] = sp; rn[t] = sn;
    __syncthreads();
    for (int s = 128; s > 0; s >>= 1) {
        if (t < s) { rp[t] += rp[t + s]; rn[t] += rn[t + s]; }
        __syncthreads();
    }
    uint32_t pos = rp[0], neg = rn[0];
    uint32_t cutoff = 3u * pos; if (cutoff < 1u) cutoff = 1u;
    if (neg <= cutoff) return;     // uniform across grid: no disabling at all

    // 2a. coarse-16 row hist from summaries (6 KB).
    if (t < 64) {
        int d = t >> 3, part = t & 7;
        const uint4* q4 = (const uint4*)(w + WS_BH4 + (b * 8 + d) * NBLK + part * 24);
        uint32_t c = 0;
#pragma unroll
        for (int k = 0; k < 6; ++k) { uint4 v = q4[k]; c += v.x + v.y + v.z + v.w; }
        s4p[t] = c;
    }
    __syncthreads();
    if (t < 8) {
        uint32_t c = 0;
#pragma unroll
        for (int k = 0; k < 8; ++k) c += s4p[t * 8 + k];
        hb[2 * t] = c & 0xFFFFu; hb[2 * t + 1] = c >> 16;
    }
    __syncthreads();
    if (t == 0) {
        uint32_t cum = 0; int C4 = -1; uint32_t base4 = 0;
        for (int c = 15; c >= 0; --c) {
            if (cum + hb[c] >= cutoff) { C4 = c; base4 = cum; break; }
            cum += hb[c];
        }
        sC4 = C4; sB4 = base4;
    }
    __syncthreads();
    int C4 = sC4;
    if (C4 < 0) return;            // row has < cutoff label-0 -> keep all

    // 2b. fine scan inside coarse bin C4 (6 KB).
    if (t < 64) {
        int d = t >> 3, part = t & 7;
        const uint4* q4 = (const uint4*)(w + WS_BH + (b * 128 + 8 * C4 + d) * NBLK + part * 24);
        uint32_t c = 0;
#pragma unroll
        for (int k = 0; k < 6; ++k) { uint4 v = q4[k]; c += v.x + v.y + v.z + v.w; }
        s4p[t] = c;
    }
    __syncthreads();
    if (t < 8) {
        uint32_t c = 0;
#pragma unroll
        for (int k = 0; k < 8; ++k) c += s4p[t * 8 + k];
        hb[2 * t] = c & 0xFFFFu; hb[2 * t + 1] = c >> 16;
    }
    __syncthreads();
    if (t == 0) {
        uint32_t cum = sB4; int C = -1; uint32_t base = 0;
        for (int j = 15; j >= 0; --j) {
            if (cum + hb[j] >= cutoff) { C = 16 * C4 + j; base = cum; break; }
            cum += hb[j];
        }
        sC = C; sBase = base;      // guaranteed found: coarse bin crossed cutoff
    }
    __syncthreads();
    int C = sC;

    // 4a. gather bin-C entries from segments: thread t<192 handles tile t.
    if (t < NBLK) {
        uint32_t cw = w[WS_BH + (b * 128 + (C >> 1)) * NBLK + t];
        uint32_t cnt_t = (C & 1) ? (cw >> 16) : (cw & 0xFFFFu);
        if (cnt_t <= SEGC) {
            const uint32_t* sg = seg +
                (((uint32_t)b * 256 + (uint32_t)C) * NBLK + (uint32_t)t) * SEGC;
            for (uint32_t k = 0; k < cnt_t; ++k) {
                uint32_t v = sg[k];
                uint32_t p_ = atomicAdd(&scnt, 1u);
                if (p_ < CAP) { lu[p_] = v >> 8; li[p_] = (uint32_t)t * 256u + (v & 255u); }
            }
        } else {
            // overflow (P ~ 1e-8): scan this tile's 256 rnk words directly.
            const uint32_t* rr = rnk + (size_t)b * NN + (size_t)t * 256;
            for (int k = 0; k < 256; ++k) {
                uint32_t val = rr[k];
                if ((val & 3u) == 2u && (int)((val >> 2) >> 15) == C) {
                    uint32_t p_ = atomicAdd(&scnt, 1u);
                    if (p_ < CAP) { lu[p_] = val >> 2; li[p_] = (uint32_t)t * 256u + (uint32_t)k; }
                }
            }
        }
    }

    // 4b. own chunk: fine bin < C -> disabled (768 anchors, uint4 reads).
    {
        const uint4* r4 = (const uint4*)(rnk + (size_t)b * NN + (size_t)ch * CHSZ);
        if (t < CHSZ / 4) {
            uint4 v = r4[t];
            uint32_t vv[4] = {v.x, v.y, v.z, v.w};
#pragma unroll
            for (int k = 0; k < 4; ++k) {
                uint32_t val = vv[k];
                if ((val & 3u) == 2u && (int)((val >> 2) >> 15) < C) {
                    int i = ch * CHSZ + t * 4 + k;
                    out[((size_t)b * NN + i) * 5] = -1.0f;
                }
            }
        }
    }
    __syncthreads();

    // 5. exact rank resolution for boundary entries in MY chunk.
    uint32_t cnt = scnt; if (cnt > CAP) cnt = CAP;
    uint32_t baseRank = sBase;
    for (uint32_t k = t; k < cnt; k += 256) {
        uint32_t u = lu[k], n = li[k];
        if (n / (uint32_t)CHSZ != (uint32_t)ch) continue;
        uint32_t r = baseRank;
        for (uint32_t j = 0; j < cnt; ++j) {
            // descending u, ties by smaller index first (stable argsort)
            r += (lu[j] > u || (lu[j] == u && li[j] < n)) ? 1u : 0u;
        }
        if (r >= cutoff) out[((size_t)b * NN + n) * 5] = -1.0f;
    }
}

// Fallback post kernel if ws is too small for rnk/segments (never taken with
// the observed 256 MiB ws; kept for safety).
__global__ __launch_bounds__(256) void k_post_slow(float* __restrict__ out,
                                                   const uint32_t* __restrict__ w) {
    const int b = blockIdx.y;
    const int ch = blockIdx.x;
    const int t = threadIdx.x;
    __shared__ uint32_t rp[256], rn[256];
    __shared__ uint32_t sph[256];
    __shared__ uint32_t hcnt[256];
    __shared__ uint32_t lu[CAP], li[CAP];
    __shared__ uint32_t scnt;
    __shared__ int sC;
    __shared__ uint32_t sBase;
    if (t == 0) scnt = 0;
    uint32_t sp = 0, sn = 0;
    {
        const uint4* p4 = (const uint4*)(w + WS_PART);
#pragma unroll
        for (int k = 0; k < 3; ++k) {
            uint4 v = p4[t + k * 256];
            sp += (v.x >> 16) + (v.y >> 16) + (v.z >> 16) + (v.w >> 16);
            sn += (v.x & 0xFFFFu) + (v.y & 0xFFFFu) + (v.z & 0xFFFFu) + (v.w & 0xFFFFu);
        }
    }
    rp[t] = sp; rn[t] = sn;
    __syncthreads();
    for (int s = 128; s > 0; s >>= 1) {
        if (t < s) { rp[t] += rp[t + s]; rn[t] += rn[t + s]; }
        __syncthreads();
    }
    uint32_t pos = rp[0], neg = rn[0];
    uint32_t cutoff = 3u * pos; if (cutoff < 1u) cutoff = 1u;
    if (neg <= cutoff) return;
    {
        int d = t >> 1, half = t & 1;
        const uint4* h4 = (const uint4*)(w + WS_BH + (b * 128 + d) * NBLK + half * 96);
        uint32_t c = 0;
#pragma unroll 4
        for (int k = 0; k < 24; ++k) { uint4 v = h4[k]; c += v.x + v.y + v.z + v.w; }
        sph[t] = c;
    }
    __syncthreads();
    if (t < 128) {
        uint32_t v0 = sph[2 * t], v1 = sph[2 * t + 1];
        hcnt[2 * t]     = (v0 & 0xFFFFu) + (v1 & 0xFFFFu);
        hcnt[2 * t + 1] = (v0 >> 16) + (v1 >> 16);
    }
    __syncthreads();
    if (t == 0) {
        uint32_t cum = 0; int C = -1; uint32_t base = 0;
        for (int c = 255; c >= 0; --c) {
            if (cum + hcnt[c] >= cutoff) { C = c; base = cum; break; }
            cum += hcnt[c];
        }
        sC = C; sBase = base;
    }
    __syncthreads();
    int C = sC;
    if (C < 0) return;
    for (int i = t; i < NN; i += 256) {
        uint32_t idx = (uint32_t)(b * NN + i);
        if (out[(size_t)idx * 5] == 0.0f) {
            uint32_t u = threefry_bits(idx) >> 9;
            if ((int)(u >> 15) == C) {
                uint32_t p_ = atomicAdd(&scnt, 1u);
                if (p_ < CAP) { lu[p_] = u; li[p_] = (uint32_t)i; }
            }
        }
    }
    for (int i2 = t; i2 < CHSZ; i2 += 256) {
        int i = ch * CHSZ + i2;
        uint32_t idx = (uint32_t)(b * NN + i);
        if (out[(size_t)idx * 5] == 0.0f) {
            uint32_t u = threefry_bits(idx) >> 9;
            if ((int)(u >> 15) < C) out[(size_t)idx * 5] = -1.0f;
        }
    }
    __syncthreads();
    uint32_t cnt = scnt; if (cnt > CAP) cnt = CAP;
    uint32_t baseRank = sBase;
    for (uint32_t k = t; k < cnt; k += 256) {
        uint32_t u = lu[k], n = li[k];
        if (n / (uint32_t)CHSZ != (uint32_t)ch) continue;
        uint32_t r = baseRank;
        for (uint32_t j = 0; j < cnt; ++j)
            r += (lu[j] > u || (lu[j] == u && li[j] < n)) ? 1u : 0u;
        if (r >= cutoff) out[((size_t)b * NN + n) * 5] = -1.0f;
    }
}

extern "C" void kernel_launch(void* const* d_in, const int* in_sizes, int n_in,
                              void* d_out, int out_size, void* d_ws, size_t ws_size,
                              hipStream_t stream) {
    // d_in[0] = cls_scores (shape-relevant only, never read)
    const float4* gt  = (const float4*)d_in[1];
    const float4* anc = (const float4*)d_in[2];
    float* out = (float*)d_out;
    uint32_t* w = (uint32_t*)d_ws;
    bool big = (ws_size >= WS_NEED_ALL);
    uint32_t* rnk = big ? (w + WS_RNK) : (uint32_t*)nullptr;
    uint32_t* seg = big ? (w + WS_SEG) : (uint32_t*)nullptr;

    k_main<<<dim3(NBLK, NB), 256, 0, stream>>>(gt, anc, out, w, rnk, seg);
    if (big) {
        k_post<<<dim3(NCH, NB), 256, 0, stream>>>(out, w, rnk, seg);
    } else {
        k_post_slow<<<dim3(NCH, NB), 256, 0, stream>>>(out, w);
    }
}